// Round 4
// baseline (4299.440 us; speedup 1.0000x reference)
//
#include <hip/hip_runtime.h>

// 2-layer GCN, R16: R15 (chunked LDS-accumulator aggregation) + workspace fix.
// R15 container death attributed to workspace overflow: bhist/bbase grew to
// 2x10.4MB, total ~73MB. R16 aliases bhist->hr and bbase->h2 (both dead
// during staging; first written strictly after last staging read), and drops
// the unused row_ptr scan chain (CSR deleted in R15; dinv comes straight from
// cnt). Total workspace ~52MB < R12's proven ~67MB.
// Design (unchanged from R15): pairs two-level sorted by (dst-bucket[128],
// src-chunk[8192]); one block per bucket accumulates f32 in LDS (64KB dyn,
// 2 blocks/CU) streaming pairs chunk-major -> h gathers hit a resident 2MB
// window (streaming beyond-L2 traffic instead of random misses).
// h1/h2 feature-interleaved (u32 = f | f+HALF<<16) so one u32 gather feeds
// two conflict-free stride-1 LDS atomicAdds per edge.

#define N_NODES 100000
#define NBLK2 256          // staging partition blocks
#define NBUCK2 782         // ceil(100000/128) dst buckets of 128
#define NCH 13             // src chunks of 8192 (s>>13)
#define NKEY (NBUCK2 * NCH) // 10166

typedef __attribute__((ext_vector_type(8))) short short8;
typedef __attribute__((ext_vector_type(4))) float f32x4;

// ---------- bf16 helpers (RN-even) ----------
__device__ __forceinline__ unsigned short f2bf(float f) {
    union { float f; unsigned u; } c; c.f = f;
    unsigned r = (c.u + 0x7fffu + ((c.u >> 16) & 1u)) >> 16;
    return (unsigned short)r;
}
__device__ __forceinline__ float2 bfpair(unsigned u) {
    union { float f; unsigned u; } a, b;
    a.u = u << 16; b.u = u & 0xffff0000u;
    return make_float2(a.f, b.f);
}
__device__ __forceinline__ unsigned packbf(float a, float b) {
    return (unsigned)f2bf(a) | ((unsigned)f2bf(b) << 16);
}

// ---------- edge dtype detection (one wave) ----------
__global__ void detect64_k(const unsigned long long* __restrict__ ei, int* __restrict__ flag) {
    unsigned long long v = ei[threadIdx.x & 63];
    unsigned long long bad = __ballot(v >= (1ULL << 32));
    if (threadIdx.x == 0) *flag = (bad == 0ULL) ? 1 : 0;
}

__device__ __forceinline__ int edge_at(const void* ei, int is64, long long idx) {
    if (is64) return (int)((const long long*)ei)[idx];
    return ((const int*)ei)[idx];
}

// ---------- pass 1: per-block [bucket x chunk] LDS histogram, block-major out ----------
__global__ __launch_bounds__(256) void count1_k(const void* __restrict__ ei,
                                                const int* __restrict__ flag,
                                                int* __restrict__ bhist, int E) {
    __shared__ int lh[NKEY];
    int t = threadIdx.x;
    for (int i = t; i < NKEY; i += 256) lh[i] = 0;
    __syncthreads();
    int is64 = *flag;
    int C = (E + NBLK2 - 1) / NBLK2;
    int lo = blockIdx.x * C;
    int hi = lo + C; if (hi > E) hi = E;
    for (int e = lo + t; e < hi; e += 256) {
        int s = edge_at(ei, is64, e);
        int d = edge_at(ei, is64, (long long)E + e);
        if ((unsigned)d >= (unsigned)N_NODES) continue;
        if ((unsigned)s >= (unsigned)N_NODES) s = 0;
        atomicAdd(&lh[(d >> 7) * NCH + (s >> 13)], 1);
    }
    __syncthreads();
    int* dst = bhist + (size_t)blockIdx.x * NKEY;   // block-major: coalesced
    for (int i = t; i < NKEY; i += 256) dst[i] = lh[i];
}

// ---------- column sums over partitions (coalesced across keys) ----------
__global__ void colsum_k(const int* __restrict__ bhist, int* __restrict__ colsum) {
    int k = blockIdx.x * 256 + threadIdx.x;
    if (k >= NKEY) return;
    int s = 0;
#pragma unroll 4
    for (int b = 0; b < NBLK2; ++b) s += bhist[(size_t)b * NKEY + k];
    colsum[k] = s;
}

// ---------- generic exclusive scan, 1024 elems/block ----------
__global__ void scan1_k(const int* __restrict__ cnt, int* __restrict__ partial,
                        int* __restrict__ bsum, int n) {
    __shared__ int sm[256];
    int t = threadIdx.x;
    int base = blockIdx.x * 1024 + t * 4;
    int v[4]; int loc = 0;
#pragma unroll
    for (int j = 0; j < 4; ++j) { v[j] = (base + j < n) ? cnt[base + j] : 0; loc += v[j]; }
    sm[t] = loc; __syncthreads();
    for (int off = 1; off < 256; off <<= 1) {
        int x = (t >= off) ? sm[t - off] : 0;
        __syncthreads();
        sm[t] += x;
        __syncthreads();
    }
    int incl = sm[t];
    int run = incl - loc;
    if (t == 255) bsum[blockIdx.x] = incl;
#pragma unroll
    for (int j = 0; j < 4; ++j) {
        if (base + j < n) partial[base + j] = run;
        run += v[j];
    }
}

// exclusive scan of block sums in place (16 per thread, up to 4096)
__global__ void scan2_k(int* __restrict__ bsum, int nb) {
    __shared__ int sm[256];
    int t = threadIdx.x;
    int v[16]; int loc = 0;
#pragma unroll
    for (int i = 0; i < 16; ++i) {
        int idx = t * 16 + i;
        v[i] = (idx < nb) ? bsum[idx] : 0;
        loc += v[i];
    }
    sm[t] = loc; __syncthreads();
    for (int off = 1; off < 256; off <<= 1) {
        int x = (t >= off) ? sm[t - off] : 0;
        __syncthreads();
        sm[t] += x;
        __syncthreads();
    }
    int run = sm[t] - loc;
#pragma unroll
    for (int i = 0; i < 16; ++i) {
        int idx = t * 16 + i;
        if (idx < nb) bsum[idx] = run;
        run += v[i];
    }
}

// finalize key-base scan in place; also emit total valid count
__global__ void scanadd_k(const int* __restrict__ bsum, int* __restrict__ arr,
                          const int* __restrict__ raw, int* __restrict__ tot, int n) {
    int base = blockIdx.x * 1024 + threadIdx.x * 4;
    int add = bsum[blockIdx.x];
#pragma unroll
    for (int j = 0; j < 4; ++j) {
        int i = base + j;
        if (i < n) {
            int v = arr[i] + add;
            arr[i] = v;
            if (i == n - 1) *tot = v + raw[i];
        }
    }
}

// per-(blk,key) base = keybase[key] + prefix over partitions (coalesced)
__global__ void colprefix_k(const int* __restrict__ bhist, const int* __restrict__ keybase,
                            int* __restrict__ bbase) {
    int k = blockIdx.x * 256 + threadIdx.x;
    if (k >= NKEY) return;
    int run = keybase[k];
#pragma unroll 8
    for (int b = 0; b < NBLK2; ++b) {
        size_t i = (size_t)b * NKEY + k;
        int c = bhist[i];
        bbase[i] = run;
        run += c;
    }
}

// dinv straight from degree (no CSR / row_ptr needed anymore)
__global__ void dinv_k(const int* __restrict__ cnt, float* __restrict__ dinv, int n) {
    int i = blockIdx.x * 256 + threadIdx.x;
    if (i < n) dinv[i] = rsqrtf((float)(cnt[i] + 1));  // +1 self-loop
}

// ---------- pass 2: staging write sorted by (bucket, chunk) ----------
__global__ __launch_bounds__(256) void write1_k(const void* __restrict__ ei,
                                                const int* __restrict__ flag,
                                                const int* __restrict__ bbase,
                                                unsigned* __restrict__ pairs, int E) {
    __shared__ int lofs[NKEY];
    int t = threadIdx.x;
    const int* src0 = bbase + (size_t)blockIdx.x * NKEY;
    for (int i = t; i < NKEY; i += 256) lofs[i] = src0[i];
    __syncthreads();
    int is64 = *flag;
    int C = (E + NBLK2 - 1) / NBLK2;
    int lo = blockIdx.x * C;
    int hi = lo + C; if (hi > E) hi = E;
    for (int e = lo + t; e < hi; e += 256) {
        int s = edge_at(ei, is64, e);
        int d = edge_at(ei, is64, (long long)E + e);
        if ((unsigned)d >= (unsigned)N_NODES) continue;
        if ((unsigned)s >= (unsigned)N_NODES) s = 0;
        int key = (d >> 7) * NCH + (s >> 13);
        int p = atomicAdd(&lofs[key], 1);
        pairs[p] = (unsigned)s | ((unsigned)(d & 127) << 17);
    }
}

// ---------- degrees from staged pairs: one block per bucket ----------
__global__ __launch_bounds__(256) void degree_k(const unsigned* __restrict__ pairs,
                                                const int* __restrict__ keybase,
                                                const int* __restrict__ tot,
                                                int* __restrict__ cnt, int Nn) {
    __shared__ int lh[128];
    int b = blockIdx.x;
    int t = threadIdx.x;
    if (t < 128) lh[t] = 0;
    __syncthreads();
    int lo = keybase[b * NCH];
    int hi = (b == NBUCK2 - 1) ? *tot : keybase[(b + 1) * NCH];
    for (int i = lo + t; i < hi; i += 256) {
        unsigned p = __builtin_nontemporal_load(pairs + i);
        atomicAdd(&lh[p >> 17], 1);
    }
    __syncthreads();
    int n0 = b << 7;
    if (t < 128 && n0 + t < Nn) cnt[n0 + t] = lh[t];
}

// ---------- weight prep: W^T in bf16 ----------
__global__ void prep_w_k(const float* __restrict__ W1, const float* __restrict__ W2,
                         unsigned short* __restrict__ w1bf, unsigned short* __restrict__ w2bf) {
    int i = blockIdx.x * 256 + threadIdx.x;
    if (i < 128 * 128) { int k = i >> 7, f = i & 127; w1bf[f * 128 + k] = f2bf(W1[i]); }
    if (i < 128 * 64)  { int k = i >> 6, f = i & 63;  w2bf[f * 128 + k] = f2bf(W2[i]); }
}

// ---------- GEMM1 (MFMA): h1[n] = dinv[n]*(x @ W1), feature-interleaved ----------
// h1[n][q] u32 = bf(feat q) | bf(feat q+64) << 16, q < 64
__global__ __launch_bounds__(256) void gemm1_k(const float* __restrict__ x,
                                               const unsigned short* __restrict__ w1bf,
                                               const float* __restrict__ dinv,
                                               unsigned* __restrict__ h1, int Nn) {
    __shared__ __align__(16) unsigned short sA[128][136];  // W1^T [feat][k]
    __shared__ __align__(16) unsigned short sB[64][136];   // x [node][k] bf16
    int tid = threadIdx.x;
    int n0g = blockIdx.x * 64;
    {
        const uint4* src = (const uint4*)w1bf;
#pragma unroll
        for (int l = 0; l < 8; ++l) {
            int idx = tid + l * 256;
            int f = idx >> 4, kq = idx & 15;
            *(uint4*)&sA[f][kq * 8] = src[idx];
        }
    }
    {
        int n = tid >> 2, kq = tid & 3;
        int gn = n0g + n; if (gn >= Nn) gn = Nn - 1;
        const float4* xr = (const float4*)(x + (size_t)gn * 128 + kq * 32);
        unsigned short* dst = &sB[n][kq * 32];
#pragma unroll
        for (int i = 0; i < 8; ++i) {
            float4 v = xr[i];
            dst[i * 4 + 0] = f2bf(v.x); dst[i * 4 + 1] = f2bf(v.y);
            dst[i * 4 + 2] = f2bf(v.z); dst[i * 4 + 3] = f2bf(v.w);
        }
    }
    __syncthreads();
    int wave = tid >> 6, lane = tid & 63;
    int quad = lane >> 4, l16 = lane & 15;
    f32x4 z = {0.f, 0.f, 0.f, 0.f};
    f32x4 acc[8];
#pragma unroll
    for (int t = 0; t < 8; ++t) acc[t] = z;
#pragma unroll
    for (int kk = 0; kk < 4; ++kk) {
        int kb = kk * 32 + quad * 8;
        short8 a = *(const short8*)&sB[wave * 16 + l16][kb];
#pragma unroll
        for (int ft = 0; ft < 8; ++ft) {
            short8 b = *(const short8*)&sA[ft * 16 + l16][kb];
            acc[ft] = __builtin_amdgcn_mfma_f32_16x16x32_bf16(a, b, acc[ft], 0, 0, 0);
        }
    }
    float dv[4];
#pragma unroll
    for (int r = 0; r < 4; ++r) {
        int gn = n0g + wave * 16 + quad * 4 + r;
        if (gn >= Nn) gn = Nn - 1;
        dv[r] = dinv[gn];
    }
    __syncthreads();  // reuse sA as transpose buffer
    unsigned short (*sC)[136] = sA;
#pragma unroll
    for (int ft = 0; ft < 8; ++ft)
#pragma unroll
        for (int r = 0; r < 4; ++r)
            sC[wave * 16 + quad * 4 + r][ft * 16 + l16] = f2bf(dv[r] * acc[ft][r]);
    __syncthreads();
#pragma unroll
    for (int l = 0; l < 4; ++l) {
        int idx = tid + l * 256;
        int row = idx >> 4, g = idx & 15;
        int gn = n0g + row;
        if (gn < Nn) {
            ushort4 A = *(ushort4*)&sC[row][g * 4];
            ushort4 B = *(ushort4*)&sC[row][g * 4 + 64];
            uint4 o;
            o.x = (unsigned)A.x | ((unsigned)B.x << 16);
            o.y = (unsigned)A.y | ((unsigned)B.y << 16);
            o.z = (unsigned)A.z | ((unsigned)B.z << 16);
            o.w = (unsigned)A.w | ((unsigned)B.w << 16);
            *(uint4*)&h1[(size_t)gn * 64 + g * 4] = o;
        }
    }
}

// ---------- GEMM2 (MFMA): h2[n] = dinv[n]*(hr @ W2), feature-interleaved ----------
// h2[n][q] u32 = bf(feat q) | bf(feat q+32) << 16, q < 32
__global__ __launch_bounds__(256) void gemm2_k(const unsigned* __restrict__ hr,
                                               const unsigned short* __restrict__ w2bf,
                                               const float* __restrict__ dinv,
                                               unsigned* __restrict__ h2, int Nn) {
    __shared__ __align__(16) unsigned short sA[64][136];
    __shared__ __align__(16) unsigned short sB[64][136];
    int tid = threadIdx.x;
    int n0g = blockIdx.x * 64;
    {
        const uint4* src = (const uint4*)w2bf;
#pragma unroll
        for (int l = 0; l < 4; ++l) {
            int idx = tid + l * 256;
            int f = idx >> 4, kq = idx & 15;
            *(uint4*)&sA[f][kq * 8] = src[idx];
        }
    }
    {
        const uint4* src = (const uint4*)hr;
#pragma unroll
        for (int l = 0; l < 4; ++l) {
            int idx = tid + l * 256;
            int row = idx >> 4, q = idx & 15;
            int gn = n0g + row; if (gn >= Nn) gn = Nn - 1;
            *(uint4*)&sB[row][q * 8] = src[(size_t)gn * 16 + q];
        }
    }
    __syncthreads();
    int wave = tid >> 6, lane = tid & 63;
    int quad = lane >> 4, l16 = lane & 15;
    f32x4 z = {0.f, 0.f, 0.f, 0.f};
    f32x4 acc[4];
#pragma unroll
    for (int t = 0; t < 4; ++t) acc[t] = z;
#pragma unroll
    for (int kk = 0; kk < 4; ++kk) {
        int kb = kk * 32 + quad * 8;
        short8 a = *(const short8*)&sB[wave * 16 + l16][kb];
#pragma unroll
        for (int ft = 0; ft < 4; ++ft) {
            short8 b = *(const short8*)&sA[ft * 16 + l16][kb];
            acc[ft] = __builtin_amdgcn_mfma_f32_16x16x32_bf16(a, b, acc[ft], 0, 0, 0);
        }
    }
    float dv[4];
#pragma unroll
    for (int r = 0; r < 4; ++r) {
        int gn = n0g + wave * 16 + quad * 4 + r;
        if (gn >= Nn) gn = Nn - 1;
        dv[r] = dinv[gn];
    }
    __syncthreads();
    unsigned short (*sC)[136] = sA;
#pragma unroll
    for (int ft = 0; ft < 4; ++ft)
#pragma unroll
        for (int r = 0; r < 4; ++r)
            sC[wave * 16 + quad * 4 + r][ft * 16 + l16] = f2bf(dv[r] * acc[ft][r]);
    __syncthreads();
#pragma unroll
    for (int l = 0; l < 2; ++l) {
        int idx = tid + l * 256;
        int row = idx >> 3, g = idx & 7;
        int gn = n0g + row;
        if (gn < Nn) {
            ushort4 A = *(ushort4*)&sC[row][g * 4];
            ushort4 B = *(ushort4*)&sC[row][g * 4 + 32];
            uint4 o;
            o.x = (unsigned)A.x | ((unsigned)B.x << 16);
            o.y = (unsigned)A.y | ((unsigned)B.y << 16);
            o.z = (unsigned)A.z | ((unsigned)B.z << 16);
            o.w = (unsigned)A.w | ((unsigned)B.w << 16);
            *(uint4*)&h2[(size_t)gn * 32 + g * 4] = o;
        }
    }
}

// ---------- agg1: block=bucket(128 dst), LDS f32 accum, chunk-ordered stream ----------
// out[dst] = relu( di * (sum h'[src] + h'[self]) + b ), out in normal feat order
__global__ __launch_bounds__(512) void agg1_k(const unsigned* __restrict__ h,
                                              const unsigned* __restrict__ pairs,
                                              const int* __restrict__ keybase,
                                              const int* __restrict__ tot,
                                              const float* __restrict__ dinv,
                                              const float* __restrict__ bias,
                                              unsigned* __restrict__ out, int Nn) {
    extern __shared__ float acc[];   // [128][128]
    int tid = threadIdx.x, lane = tid & 63, wave = tid >> 6;
    int b = blockIdx.x, n0 = b << 7;
    // init with self rows (h already dinv-prescaled; interleaved (q, q+64))
    for (int i = tid; i < 128 * 64; i += 512) {
        int row = i >> 6, q = i & 63;
        unsigned u = (n0 + row < Nn) ? h[(size_t)(n0 + row) * 64 + q] : 0u;
        float2 v = bfpair(u);
        acc[row * 128 + q] = v.x;
        acc[row * 128 + 64 + q] = v.y;
    }
    __syncthreads();
    int lo = keybase[b * NCH];
    int hi = (b == NBUCK2 - 1) ? *tot : keybase[(b + 1) * NCH];
    for (int base = lo + wave * 64; base < hi; base += 512) {
        int idx = base + lane;
        unsigned pv = pairs[(idx < hi) ? idx : (hi - 1)];
        int m = hi - base; if (m > 64) m = 64;
        int j = 0;
        for (; j + 4 <= m; j += 4) {
            unsigned p0 = __shfl(pv, j),     p1 = __shfl(pv, j + 1);
            unsigned p2 = __shfl(pv, j + 2), p3 = __shfl(pv, j + 3);
            unsigned u0 = h[((p0 & 0x1FFFFu) << 6) + lane];
            unsigned u1 = h[((p1 & 0x1FFFFu) << 6) + lane];
            unsigned u2 = h[((p2 & 0x1FFFFu) << 6) + lane];
            unsigned u3 = h[((p3 & 0x1FFFFu) << 6) + lane];
            float2 v0 = bfpair(u0); float* a0 = &acc[((p0 >> 17) << 7) + lane];
            atomicAdd(a0, v0.x); atomicAdd(a0 + 64, v0.y);
            float2 v1 = bfpair(u1); float* a1 = &acc[((p1 >> 17) << 7) + lane];
            atomicAdd(a1, v1.x); atomicAdd(a1 + 64, v1.y);
            float2 v2 = bfpair(u2); float* a2 = &acc[((p2 >> 17) << 7) + lane];
            atomicAdd(a2, v2.x); atomicAdd(a2 + 64, v2.y);
            float2 v3 = bfpair(u3); float* a3 = &acc[((p3 >> 17) << 7) + lane];
            atomicAdd(a3, v3.x); atomicAdd(a3 + 64, v3.y);
        }
        for (; j < m; ++j) {
            unsigned p = __shfl(pv, j);
            unsigned u = h[((p & 0x1FFFFu) << 6) + lane];
            float2 v = bfpair(u);
            float* a = &acc[((p >> 17) << 7) + lane];
            atomicAdd(a, v.x); atomicAdd(a + 64, v.y);
        }
    }
    __syncthreads();
    int nn = Nn - n0; if (nn > 128) nn = 128;
    for (int i = tid; i < nn * 64; i += 512) {
        int row = i >> 6, q = i & 63;
        float di = dinv[n0 + row];
        float2 vv = *(float2*)&acc[row * 128 + 2 * q];
        float r0 = fmaxf(fmaf(di, vv.x, bias[2 * q]), 0.f);
        float r1 = fmaxf(fmaf(di, vv.y, bias[2 * q + 1]), 0.f);
        out[(size_t)(n0 + row) * 64 + q] = packbf(r0, r1);
    }
}

// ---------- agg2: block=bucket(128 dst), 32KB LDS accum, 2 edges/wave-step ----------
__global__ __launch_bounds__(512) void agg2_k(const unsigned* __restrict__ h,
                                              const unsigned* __restrict__ pairs,
                                              const int* __restrict__ keybase,
                                              const int* __restrict__ tot,
                                              const float* __restrict__ dinv,
                                              const float* __restrict__ bias,
                                              float* __restrict__ out, int Nn) {
    __shared__ float acc[128 * 64];
    int tid = threadIdx.x, lane = tid & 63, wave = tid >> 6;
    int half = lane >> 5, fl = lane & 31;
    int b = blockIdx.x, n0 = b << 7;
    for (int i = tid; i < 128 * 32; i += 512) {
        int row = i >> 5, q = i & 31;
        unsigned u = (n0 + row < Nn) ? h[(size_t)(n0 + row) * 32 + q] : 0u;
        float2 v = bfpair(u);
        acc[row * 64 + q] = v.x;
        acc[row * 64 + 32 + q] = v.y;
    }
    __syncthreads();
    int lo = keybase[b * NCH];
    int hi = (b == NBUCK2 - 1) ? *tot : keybase[(b + 1) * NCH];
    for (int base = lo + wave * 64; base < hi; base += 512) {
        int idx = base + lane;
        unsigned pv = pairs[(idx < hi) ? idx : (hi - 1)];
        int m = hi - base; if (m > 64) m = 64;
        int j = 0;
        for (; j + 8 <= m; j += 8) {
            unsigned p0 = __shfl(pv, j + half);
            unsigned p1 = __shfl(pv, j + 2 + half);
            unsigned p2 = __shfl(pv, j + 4 + half);
            unsigned p3 = __shfl(pv, j + 6 + half);
            unsigned u0 = h[((p0 & 0x1FFFFu) << 5) + fl];
            unsigned u1 = h[((p1 & 0x1FFFFu) << 5) + fl];
            unsigned u2 = h[((p2 & 0x1FFFFu) << 5) + fl];
            unsigned u3 = h[((p3 & 0x1FFFFu) << 5) + fl];
            float2 v0 = bfpair(u0); float* a0 = &acc[((p0 >> 17) << 6) + fl];
            atomicAdd(a0, v0.x); atomicAdd(a0 + 32, v0.y);
            float2 v1 = bfpair(u1); float* a1 = &acc[((p1 >> 17) << 6) + fl];
            atomicAdd(a1, v1.x); atomicAdd(a1 + 32, v1.y);
            float2 v2 = bfpair(u2); float* a2 = &acc[((p2 >> 17) << 6) + fl];
            atomicAdd(a2, v2.x); atomicAdd(a2 + 32, v2.y);
            float2 v3 = bfpair(u3); float* a3 = &acc[((p3 >> 17) << 6) + fl];
            atomicAdd(a3, v3.x); atomicAdd(a3 + 32, v3.y);
        }
        for (; j < m; j += 2) {
            int q = j + half;
            unsigned p = __shfl(pv, (q < m) ? q : j);
            if (q < m) {
                unsigned u = h[((p & 0x1FFFFu) << 5) + fl];
                float2 v = bfpair(u);
                float* a = &acc[((p >> 17) << 6) + fl];
                atomicAdd(a, v.x); atomicAdd(a + 32, v.y);
            }
        }
    }
    __syncthreads();
    int nn = Nn - n0; if (nn > 128) nn = 128;
    for (int i = tid; i < nn * 64; i += 512) {
        int row = i >> 6, f = i & 63;
        float di = dinv[n0 + row];
        out[(size_t)(n0 + row) * 64 + f] = fmaf(di, acc[row * 64 + f], bias[f]);
    }
}

// ---------- launch ----------
extern "C" void kernel_launch(void* const* d_in, const int* in_sizes, int n_in,
                              void* d_out, int out_size, void* d_ws, size_t ws_size,
                              hipStream_t stream) {
    const float* x  = (const float*)d_in[0];
    const void*  ei = d_in[1];
    const float* W1 = (const float*)d_in[2];
    const float* b1 = (const float*)d_in[3];
    const float* W2 = (const float*)d_in[4];
    const float* b2 = (const float*)d_in[5];

    const int N = N_NODES;
    const int E = in_sizes[1] / 2;

    char* w = (char*)d_ws;
    size_t off = 0;
    auto take = [&](size_t bytes) {
        void* p = w + off;
        off = (off + bytes + 255) & ~(size_t)255;
        return p;
    };
    int*   flag    = (int*)take(2 * sizeof(int));
    int*   tot     = flag + 1;
    int*   cnt     = (int*)take((size_t)N * 4);
    int*   bsumB   = (int*)take(4096 * 4);
    int*   colsum  = (int*)take((size_t)NKEY * 4);
    int*   keybase = (int*)take((size_t)NKEY * 4);
    float* dinv    = (float*)take((size_t)N * 4);
    unsigned* pairs = (unsigned*)take((size_t)E * 4);
    unsigned short* w1bf = (unsigned short*)take(128 * 128 * 2);
    unsigned short* w2bf = (unsigned short*)take(64 * 128 * 2);
    unsigned* hr   = (unsigned*)take((size_t)N * 64 * 4);   // bf16 [N][128] normal order
    unsigned* h2   = (unsigned*)take((size_t)N * 32 * 4);   // bf16 [N][64] interleaved
    (void)ws_size; (void)n_in; (void)out_size;

    // Staging tables ALIAS onto hr/h2 (both dead until after staging):
    //   bhist last read by colprefix_k; hr first written by agg1_k (later).
    //   bbase last read by write1_k;   h2 first written by gemm2_k (later).
    // sizes: NBLK2*NKEY*4 = 10.41MB; hr = 25.6MB, h2 = 12.8MB. Fits.
    int* bhist = (int*)hr;
    int* bbase = (int*)h2;

    unsigned* h1 = (unsigned*)d_out;  // bf16 [N][128] interleaved, dead before agg2 writes

    const int nscanK = (NKEY + 1023) / 1024;   // 10
    const int ngridK = (NKEY + 255) / 256;     // 40

    detect64_k<<<1, 64, 0, stream>>>((const unsigned long long*)ei, flag);
    count1_k<<<NBLK2, 256, 0, stream>>>(ei, flag, bhist, E);
    colsum_k<<<ngridK, 256, 0, stream>>>(bhist, colsum);
    scan1_k<<<nscanK, 256, 0, stream>>>(colsum, keybase, bsumB, NKEY);
    scan2_k<<<1, 256, 0, stream>>>(bsumB, nscanK);
    scanadd_k<<<nscanK, 256, 0, stream>>>(bsumB, keybase, colsum, tot, NKEY);
    colprefix_k<<<ngridK, 256, 0, stream>>>(bhist, keybase, bbase);
    write1_k<<<NBLK2, 256, 0, stream>>>(ei, flag, bbase, pairs, E);
    degree_k<<<NBUCK2, 256, 0, stream>>>(pairs, keybase, tot, cnt, N);
    dinv_k<<<(N + 255) / 256, 256, 0, stream>>>(cnt, dinv, N);
    prep_w_k<<<64, 256, 0, stream>>>(W1, W2, w1bf, w2bf);

    gemm1_k<<<(N + 63) / 64, 256, 0, stream>>>(x, w1bf, dinv, h1, N);
    agg1_k<<<NBUCK2, 512, 128 * 128 * 4, stream>>>(h1, pairs, keybase, tot, dinv, b1, hr, N);
    gemm2_k<<<(N + 63) / 64, 256, 0, stream>>>(hr, w2bf, dinv, h2, N);
    agg2_k<<<NBUCK2, 512, 0, stream>>>(h2, pairs, keybase, tot, dinv, b2, (float*)d_out, N);
}

// Round 5
// 4295.241 us; speedup vs baseline: 1.0010x; 1.0010x over previous
//
#include <hip/hip_runtime.h>

// 2-layer GCN, R17: R16 + native LDS f32 atomics.
// R16 post-mortem: agg1 2715us, VALUBusy 1.9%, hbm 1.5% -- everything idle,
// correct results. Diagnosis: HIP atomicAdd(float*) on LDS lowers to a CAS
// retry loop (IEEE denorm compliance; native ds_add_f32 only with
// unsafe-fp-atomics). 8 waves x same-row contention -> CAS retry convoy,
// ~33K cycles per 4-edge iteration. Integer LDS atomics elsewhere are native
// ds_add_u32 -- which is why only the f32-accumulate kernels collapsed.
// R17 fix: unsafeAtomicAdd (native ds_add_f32, fire-and-forget) in agg1/agg2.
// Everything else identical to R16 (proven correct: same absmax as R12-R14).

#define N_NODES 100000
#define NBLK2 256          // staging partition blocks
#define NBUCK2 782         // ceil(100000/128) dst buckets of 128
#define NCH 13             // src chunks of 8192 (s>>13)
#define NKEY (NBUCK2 * NCH) // 10166

typedef __attribute__((ext_vector_type(8))) short short8;
typedef __attribute__((ext_vector_type(4))) float f32x4;

// ---------- bf16 helpers (RN-even) ----------
__device__ __forceinline__ unsigned short f2bf(float f) {
    union { float f; unsigned u; } c; c.f = f;
    unsigned r = (c.u + 0x7fffu + ((c.u >> 16) & 1u)) >> 16;
    return (unsigned short)r;
}
__device__ __forceinline__ float2 bfpair(unsigned u) {
    union { float f; unsigned u; } a, b;
    a.u = u << 16; b.u = u & 0xffff0000u;
    return make_float2(a.f, b.f);
}
__device__ __forceinline__ unsigned packbf(float a, float b) {
    return (unsigned)f2bf(a) | ((unsigned)f2bf(b) << 16);
}
// native LDS float add (ds_add_f32), no CAS loop
__device__ __forceinline__ void lds_fadd(float* p, float v) {
    unsafeAtomicAdd(p, v);
}

// ---------- edge dtype detection (one wave) ----------
__global__ void detect64_k(const unsigned long long* __restrict__ ei, int* __restrict__ flag) {
    unsigned long long v = ei[threadIdx.x & 63];
    unsigned long long bad = __ballot(v >= (1ULL << 32));
    if (threadIdx.x == 0) *flag = (bad == 0ULL) ? 1 : 0;
}

__device__ __forceinline__ int edge_at(const void* ei, int is64, long long idx) {
    if (is64) return (int)((const long long*)ei)[idx];
    return ((const int*)ei)[idx];
}

// ---------- pass 1: per-block [bucket x chunk] LDS histogram, block-major out ----------
__global__ __launch_bounds__(256) void count1_k(const void* __restrict__ ei,
                                                const int* __restrict__ flag,
                                                int* __restrict__ bhist, int E) {
    __shared__ int lh[NKEY];
    int t = threadIdx.x;
    for (int i = t; i < NKEY; i += 256) lh[i] = 0;
    __syncthreads();
    int is64 = *flag;
    int C = (E + NBLK2 - 1) / NBLK2;
    int lo = blockIdx.x * C;
    int hi = lo + C; if (hi > E) hi = E;
    for (int e = lo + t; e < hi; e += 256) {
        int s = edge_at(ei, is64, e);
        int d = edge_at(ei, is64, (long long)E + e);
        if ((unsigned)d >= (unsigned)N_NODES) continue;
        if ((unsigned)s >= (unsigned)N_NODES) s = 0;
        atomicAdd(&lh[(d >> 7) * NCH + (s >> 13)], 1);
    }
    __syncthreads();
    int* dst = bhist + (size_t)blockIdx.x * NKEY;   // block-major: coalesced
    for (int i = t; i < NKEY; i += 256) dst[i] = lh[i];
}

// ---------- column sums over partitions (coalesced across keys) ----------
__global__ void colsum_k(const int* __restrict__ bhist, int* __restrict__ colsum) {
    int k = blockIdx.x * 256 + threadIdx.x;
    if (k >= NKEY) return;
    int s = 0;
#pragma unroll 4
    for (int b = 0; b < NBLK2; ++b) s += bhist[(size_t)b * NKEY + k];
    colsum[k] = s;
}

// ---------- generic exclusive scan, 1024 elems/block ----------
__global__ void scan1_k(const int* __restrict__ cnt, int* __restrict__ partial,
                        int* __restrict__ bsum, int n) {
    __shared__ int sm[256];
    int t = threadIdx.x;
    int base = blockIdx.x * 1024 + t * 4;
    int v[4]; int loc = 0;
#pragma unroll
    for (int j = 0; j < 4; ++j) { v[j] = (base + j < n) ? cnt[base + j] : 0; loc += v[j]; }
    sm[t] = loc; __syncthreads();
    for (int off = 1; off < 256; off <<= 1) {
        int x = (t >= off) ? sm[t - off] : 0;
        __syncthreads();
        sm[t] += x;
        __syncthreads();
    }
    int incl = sm[t];
    int run = incl - loc;
    if (t == 255) bsum[blockIdx.x] = incl;
#pragma unroll
    for (int j = 0; j < 4; ++j) {
        if (base + j < n) partial[base + j] = run;
        run += v[j];
    }
}

// exclusive scan of block sums in place (16 per thread, up to 4096)
__global__ void scan2_k(int* __restrict__ bsum, int nb) {
    __shared__ int sm[256];
    int t = threadIdx.x;
    int v[16]; int loc = 0;
#pragma unroll
    for (int i = 0; i < 16; ++i) {
        int idx = t * 16 + i;
        v[i] = (idx < nb) ? bsum[idx] : 0;
        loc += v[i];
    }
    sm[t] = loc; __syncthreads();
    for (int off = 1; off < 256; off <<= 1) {
        int x = (t >= off) ? sm[t - off] : 0;
        __syncthreads();
        sm[t] += x;
        __syncthreads();
    }
    int run = sm[t] - loc;
#pragma unroll
    for (int i = 0; i < 16; ++i) {
        int idx = t * 16 + i;
        if (idx < nb) bsum[idx] = run;
        run += v[i];
    }
}

// finalize key-base scan in place; also emit total valid count
__global__ void scanadd_k(const int* __restrict__ bsum, int* __restrict__ arr,
                          const int* __restrict__ raw, int* __restrict__ tot, int n) {
    int base = blockIdx.x * 1024 + threadIdx.x * 4;
    int add = bsum[blockIdx.x];
#pragma unroll
    for (int j = 0; j < 4; ++j) {
        int i = base + j;
        if (i < n) {
            int v = arr[i] + add;
            arr[i] = v;
            if (i == n - 1) *tot = v + raw[i];
        }
    }
}

// per-(blk,key) base = keybase[key] + prefix over partitions (coalesced)
__global__ void colprefix_k(const int* __restrict__ bhist, const int* __restrict__ keybase,
                            int* __restrict__ bbase) {
    int k = blockIdx.x * 256 + threadIdx.x;
    if (k >= NKEY) return;
    int run = keybase[k];
#pragma unroll 8
    for (int b = 0; b < NBLK2; ++b) {
        size_t i = (size_t)b * NKEY + k;
        int c = bhist[i];
        bbase[i] = run;
        run += c;
    }
}

// dinv straight from degree (no CSR / row_ptr needed anymore)
__global__ void dinv_k(const int* __restrict__ cnt, float* __restrict__ dinv, int n) {
    int i = blockIdx.x * 256 + threadIdx.x;
    if (i < n) dinv[i] = rsqrtf((float)(cnt[i] + 1));  // +1 self-loop
}

// ---------- pass 2: staging write sorted by (bucket, chunk) ----------
__global__ __launch_bounds__(256) void write1_k(const void* __restrict__ ei,
                                                const int* __restrict__ flag,
                                                const int* __restrict__ bbase,
                                                unsigned* __restrict__ pairs, int E) {
    __shared__ int lofs[NKEY];
    int t = threadIdx.x;
    const int* src0 = bbase + (size_t)blockIdx.x * NKEY;
    for (int i = t; i < NKEY; i += 256) lofs[i] = src0[i];
    __syncthreads();
    int is64 = *flag;
    int C = (E + NBLK2 - 1) / NBLK2;
    int lo = blockIdx.x * C;
    int hi = lo + C; if (hi > E) hi = E;
    for (int e = lo + t; e < hi; e += 256) {
        int s = edge_at(ei, is64, e);
        int d = edge_at(ei, is64, (long long)E + e);
        if ((unsigned)d >= (unsigned)N_NODES) continue;
        if ((unsigned)s >= (unsigned)N_NODES) s = 0;
        int key = (d >> 7) * NCH + (s >> 13);
        int p = atomicAdd(&lofs[key], 1);
        pairs[p] = (unsigned)s | ((unsigned)(d & 127) << 17);
    }
}

// ---------- degrees from staged pairs: one block per bucket ----------
__global__ __launch_bounds__(256) void degree_k(const unsigned* __restrict__ pairs,
                                                const int* __restrict__ keybase,
                                                const int* __restrict__ tot,
                                                int* __restrict__ cnt, int Nn) {
    __shared__ int lh[128];
    int b = blockIdx.x;
    int t = threadIdx.x;
    if (t < 128) lh[t] = 0;
    __syncthreads();
    int lo = keybase[b * NCH];
    int hi = (b == NBUCK2 - 1) ? *tot : keybase[(b + 1) * NCH];
    for (int i = lo + t; i < hi; i += 256) {
        unsigned p = __builtin_nontemporal_load(pairs + i);
        atomicAdd(&lh[p >> 17], 1);
    }
    __syncthreads();
    int n0 = b << 7;
    if (t < 128 && n0 + t < Nn) cnt[n0 + t] = lh[t];
}

// ---------- weight prep: W^T in bf16 ----------
__global__ void prep_w_k(const float* __restrict__ W1, const float* __restrict__ W2,
                         unsigned short* __restrict__ w1bf, unsigned short* __restrict__ w2bf) {
    int i = blockIdx.x * 256 + threadIdx.x;
    if (i < 128 * 128) { int k = i >> 7, f = i & 127; w1bf[f * 128 + k] = f2bf(W1[i]); }
    if (i < 128 * 64)  { int k = i >> 6, f = i & 63;  w2bf[f * 128 + k] = f2bf(W2[i]); }
}

// ---------- GEMM1 (MFMA): h1[n] = dinv[n]*(x @ W1), feature-interleaved ----------
// h1[n][q] u32 = bf(feat q) | bf(feat q+64) << 16, q < 64
__global__ __launch_bounds__(256) void gemm1_k(const float* __restrict__ x,
                                               const unsigned short* __restrict__ w1bf,
                                               const float* __restrict__ dinv,
                                               unsigned* __restrict__ h1, int Nn) {
    __shared__ __align__(16) unsigned short sA[128][136];  // W1^T [feat][k]
    __shared__ __align__(16) unsigned short sB[64][136];   // x [node][k] bf16
    int tid = threadIdx.x;
    int n0g = blockIdx.x * 64;
    {
        const uint4* src = (const uint4*)w1bf;
#pragma unroll
        for (int l = 0; l < 8; ++l) {
            int idx = tid + l * 256;
            int f = idx >> 4, kq = idx & 15;
            *(uint4*)&sA[f][kq * 8] = src[idx];
        }
    }
    {
        int n = tid >> 2, kq = tid & 3;
        int gn = n0g + n; if (gn >= Nn) gn = Nn - 1;
        const float4* xr = (const float4*)(x + (size_t)gn * 128 + kq * 32);
        unsigned short* dst = &sB[n][kq * 32];
#pragma unroll
        for (int i = 0; i < 8; ++i) {
            float4 v = xr[i];
            dst[i * 4 + 0] = f2bf(v.x); dst[i * 4 + 1] = f2bf(v.y);
            dst[i * 4 + 2] = f2bf(v.z); dst[i * 4 + 3] = f2bf(v.w);
        }
    }
    __syncthreads();
    int wave = tid >> 6, lane = tid & 63;
    int quad = lane >> 4, l16 = lane & 15;
    f32x4 z = {0.f, 0.f, 0.f, 0.f};
    f32x4 acc[8];
#pragma unroll
    for (int t = 0; t < 8; ++t) acc[t] = z;
#pragma unroll
    for (int kk = 0; kk < 4; ++kk) {
        int kb = kk * 32 + quad * 8;
        short8 a = *(const short8*)&sB[wave * 16 + l16][kb];
#pragma unroll
        for (int ft = 0; ft < 8; ++ft) {
            short8 b = *(const short8*)&sA[ft * 16 + l16][kb];
            acc[ft] = __builtin_amdgcn_mfma_f32_16x16x32_bf16(a, b, acc[ft], 0, 0, 0);
        }
    }
    float dv[4];
#pragma unroll
    for (int r = 0; r < 4; ++r) {
        int gn = n0g + wave * 16 + quad * 4 + r;
        if (gn >= Nn) gn = Nn - 1;
        dv[r] = dinv[gn];
    }
    __syncthreads();  // reuse sA as transpose buffer
    unsigned short (*sC)[136] = sA;
#pragma unroll
    for (int ft = 0; ft < 8; ++ft)
#pragma unroll
        for (int r = 0; r < 4; ++r)
            sC[wave * 16 + quad * 4 + r][ft * 16 + l16] = f2bf(dv[r] * acc[ft][r]);
    __syncthreads();
#pragma unroll
    for (int l = 0; l < 4; ++l) {
        int idx = tid + l * 256;
        int row = idx >> 4, g = idx & 15;
        int gn = n0g + row;
        if (gn < Nn) {
            ushort4 A = *(ushort4*)&sC[row][g * 4];
            ushort4 B = *(ushort4*)&sC[row][g * 4 + 64];
            uint4 o;
            o.x = (unsigned)A.x | ((unsigned)B.x << 16);
            o.y = (unsigned)A.y | ((unsigned)B.y << 16);
            o.z = (unsigned)A.z | ((unsigned)B.z << 16);
            o.w = (unsigned)A.w | ((unsigned)B.w << 16);
            *(uint4*)&h1[(size_t)gn * 64 + g * 4] = o;
        }
    }
}

// ---------- GEMM2 (MFMA): h2[n] = dinv[n]*(hr @ W2), feature-interleaved ----------
// h2[n][q] u32 = bf(feat q) | bf(feat q+32) << 16, q < 32
__global__ __launch_bounds__(256) void gemm2_k(const unsigned* __restrict__ hr,
                                               const unsigned short* __restrict__ w2bf,
                                               const float* __restrict__ dinv,
                                               unsigned* __restrict__ h2, int Nn) {
    __shared__ __align__(16) unsigned short sA[64][136];
    __shared__ __align__(16) unsigned short sB[64][136];
    int tid = threadIdx.x;
    int n0g = blockIdx.x * 64;
    {
        const uint4* src = (const uint4*)w2bf;
#pragma unroll
        for (int l = 0; l < 4; ++l) {
            int idx = tid + l * 256;
            int f = idx >> 4, kq = idx & 15;
            *(uint4*)&sA[f][kq * 8] = src[idx];
        }
    }
    {
        const uint4* src = (const uint4*)hr;
#pragma unroll
        for (int l = 0; l < 4; ++l) {
            int idx = tid + l * 256;
            int row = idx >> 4, q = idx & 15;
            int gn = n0g + row; if (gn >= Nn) gn = Nn - 1;
            *(uint4*)&sB[row][q * 8] = src[(size_t)gn * 16 + q];
        }
    }
    __syncthreads();
    int wave = tid >> 6, lane = tid & 63;
    int quad = lane >> 4, l16 = lane & 15;
    f32x4 z = {0.f, 0.f, 0.f, 0.f};
    f32x4 acc[4];
#pragma unroll
    for (int t = 0; t < 4; ++t) acc[t] = z;
#pragma unroll
    for (int kk = 0; kk < 4; ++kk) {
        int kb = kk * 32 + quad * 8;
        short8 a = *(const short8*)&sB[wave * 16 + l16][kb];
#pragma unroll
        for (int ft = 0; ft < 4; ++ft) {
            short8 b = *(const short8*)&sA[ft * 16 + l16][kb];
            acc[ft] = __builtin_amdgcn_mfma_f32_16x16x32_bf16(a, b, acc[ft], 0, 0, 0);
        }
    }
    float dv[4];
#pragma unroll
    for (int r = 0; r < 4; ++r) {
        int gn = n0g + wave * 16 + quad * 4 + r;
        if (gn >= Nn) gn = Nn - 1;
        dv[r] = dinv[gn];
    }
    __syncthreads();
    unsigned short (*sC)[136] = sA;
#pragma unroll
    for (int ft = 0; ft < 4; ++ft)
#pragma unroll
        for (int r = 0; r < 4; ++r)
            sC[wave * 16 + quad * 4 + r][ft * 16 + l16] = f2bf(dv[r] * acc[ft][r]);
    __syncthreads();
#pragma unroll
    for (int l = 0; l < 2; ++l) {
        int idx = tid + l * 256;
        int row = idx >> 3, g = idx & 7;
        int gn = n0g + row;
        if (gn < Nn) {
            ushort4 A = *(ushort4*)&sC[row][g * 4];
            ushort4 B = *(ushort4*)&sC[row][g * 4 + 32];
            uint4 o;
            o.x = (unsigned)A.x | ((unsigned)B.x << 16);
            o.y = (unsigned)A.y | ((unsigned)B.y << 16);
            o.z = (unsigned)A.z | ((unsigned)B.z << 16);
            o.w = (unsigned)A.w | ((unsigned)B.w << 16);
            *(uint4*)&h2[(size_t)gn * 32 + g * 4] = o;
        }
    }
}

// ---------- agg1: block=bucket(128 dst), LDS f32 accum, chunk-ordered stream ----------
// out[dst] = relu( di * (sum h'[src] + h'[self]) + b ), out in normal feat order
__global__ __launch_bounds__(512) void agg1_k(const unsigned* __restrict__ h,
                                              const unsigned* __restrict__ pairs,
                                              const int* __restrict__ keybase,
                                              const int* __restrict__ tot,
                                              const float* __restrict__ dinv,
                                              const float* __restrict__ bias,
                                              unsigned* __restrict__ out, int Nn) {
    extern __shared__ float acc[];   // [128][128]
    int tid = threadIdx.x, lane = tid & 63, wave = tid >> 6;
    int b = blockIdx.x, n0 = b << 7;
    // init with self rows (h already dinv-prescaled; interleaved (q, q+64))
    for (int i = tid; i < 128 * 64; i += 512) {
        int row = i >> 6, q = i & 63;
        unsigned u = (n0 + row < Nn) ? h[(size_t)(n0 + row) * 64 + q] : 0u;
        float2 v = bfpair(u);
        acc[row * 128 + q] = v.x;
        acc[row * 128 + 64 + q] = v.y;
    }
    __syncthreads();
    int lo = keybase[b * NCH];
    int hi = (b == NBUCK2 - 1) ? *tot : keybase[(b + 1) * NCH];
    for (int base = lo + wave * 64; base < hi; base += 512) {
        int idx = base + lane;
        unsigned pv = pairs[(idx < hi) ? idx : (hi - 1)];
        int m = hi - base; if (m > 64) m = 64;
        int j = 0;
        for (; j + 4 <= m; j += 4) {
            unsigned p0 = __shfl(pv, j),     p1 = __shfl(pv, j + 1);
            unsigned p2 = __shfl(pv, j + 2), p3 = __shfl(pv, j + 3);
            unsigned u0 = h[((p0 & 0x1FFFFu) << 6) + lane];
            unsigned u1 = h[((p1 & 0x1FFFFu) << 6) + lane];
            unsigned u2 = h[((p2 & 0x1FFFFu) << 6) + lane];
            unsigned u3 = h[((p3 & 0x1FFFFu) << 6) + lane];
            float2 v0 = bfpair(u0); float* a0 = &acc[((p0 >> 17) << 7) + lane];
            lds_fadd(a0, v0.x); lds_fadd(a0 + 64, v0.y);
            float2 v1 = bfpair(u1); float* a1 = &acc[((p1 >> 17) << 7) + lane];
            lds_fadd(a1, v1.x); lds_fadd(a1 + 64, v1.y);
            float2 v2 = bfpair(u2); float* a2 = &acc[((p2 >> 17) << 7) + lane];
            lds_fadd(a2, v2.x); lds_fadd(a2 + 64, v2.y);
            float2 v3 = bfpair(u3); float* a3 = &acc[((p3 >> 17) << 7) + lane];
            lds_fadd(a3, v3.x); lds_fadd(a3 + 64, v3.y);
        }
        for (; j < m; ++j) {
            unsigned p = __shfl(pv, j);
            unsigned u = h[((p & 0x1FFFFu) << 6) + lane];
            float2 v = bfpair(u);
            float* a = &acc[((p >> 17) << 7) + lane];
            lds_fadd(a, v.x); lds_fadd(a + 64, v.y);
        }
    }
    __syncthreads();
    int nn = Nn - n0; if (nn > 128) nn = 128;
    for (int i = tid; i < nn * 64; i += 512) {
        int row = i >> 6, q = i & 63;
        float di = dinv[n0 + row];
        float2 vv = *(float2*)&acc[row * 128 + 2 * q];
        float r0 = fmaxf(fmaf(di, vv.x, bias[2 * q]), 0.f);
        float r1 = fmaxf(fmaf(di, vv.y, bias[2 * q + 1]), 0.f);
        out[(size_t)(n0 + row) * 64 + q] = packbf(r0, r1);
    }
}

// ---------- agg2: block=bucket(128 dst), 32KB LDS accum, 2 edges/wave-step ----------
__global__ __launch_bounds__(512) void agg2_k(const unsigned* __restrict__ h,
                                              const unsigned* __restrict__ pairs,
                                              const int* __restrict__ keybase,
                                              const int* __restrict__ tot,
                                              const float* __restrict__ dinv,
                                              const float* __restrict__ bias,
                                              float* __restrict__ out, int Nn) {
    __shared__ float acc[128 * 64];
    int tid = threadIdx.x, lane = tid & 63, wave = tid >> 6;
    int half = lane >> 5, fl = lane & 31;
    int b = blockIdx.x, n0 = b << 7;
    for (int i = tid; i < 128 * 32; i += 512) {
        int row = i >> 5, q = i & 31;
        unsigned u = (n0 + row < Nn) ? h[(size_t)(n0 + row) * 32 + q] : 0u;
        float2 v = bfpair(u);
        acc[row * 64 + q] = v.x;
        acc[row * 64 + 32 + q] = v.y;
    }
    __syncthreads();
    int lo = keybase[b * NCH];
    int hi = (b == NBUCK2 - 1) ? *tot : keybase[(b + 1) * NCH];
    for (int base = lo + wave * 64; base < hi; base += 512) {
        int idx = base + lane;
        unsigned pv = pairs[(idx < hi) ? idx : (hi - 1)];
        int m = hi - base; if (m > 64) m = 64;
        int j = 0;
        for (; j + 8 <= m; j += 8) {
            unsigned p0 = __shfl(pv, j + half);
            unsigned p1 = __shfl(pv, j + 2 + half);
            unsigned p2 = __shfl(pv, j + 4 + half);
            unsigned p3 = __shfl(pv, j + 6 + half);
            unsigned u0 = h[((p0 & 0x1FFFFu) << 5) + fl];
            unsigned u1 = h[((p1 & 0x1FFFFu) << 5) + fl];
            unsigned u2 = h[((p2 & 0x1FFFFu) << 5) + fl];
            unsigned u3 = h[((p3 & 0x1FFFFu) << 5) + fl];
            float2 v0 = bfpair(u0); float* a0 = &acc[((p0 >> 17) << 6) + fl];
            lds_fadd(a0, v0.x); lds_fadd(a0 + 32, v0.y);
            float2 v1 = bfpair(u1); float* a1 = &acc[((p1 >> 17) << 6) + fl];
            lds_fadd(a1, v1.x); lds_fadd(a1 + 32, v1.y);
            float2 v2 = bfpair(u2); float* a2 = &acc[((p2 >> 17) << 6) + fl];
            lds_fadd(a2, v2.x); lds_fadd(a2 + 32, v2.y);
            float2 v3 = bfpair(u3); float* a3 = &acc[((p3 >> 17) << 6) + fl];
            lds_fadd(a3, v3.x); lds_fadd(a3 + 32, v3.y);
        }
        for (; j < m; j += 2) {
            int q = j + half;
            unsigned p = __shfl(pv, (q < m) ? q : j);
            if (q < m) {
                unsigned u = h[((p & 0x1FFFFu) << 5) + fl];
                float2 v = bfpair(u);
                float* a = &acc[((p >> 17) << 6) + fl];
                lds_fadd(a, v.x); lds_fadd(a + 32, v.y);
            }
        }
    }
    __syncthreads();
    int nn = Nn - n0; if (nn > 128) nn = 128;
    for (int i = tid; i < nn * 64; i += 512) {
        int row = i >> 6, f = i & 63;
        float di = dinv[n0 + row];
        out[(size_t)(n0 + row) * 64 + f] = fmaf(di, acc[row * 64 + f], bias[f]);
    }
}

// ---------- launch ----------
extern "C" void kernel_launch(void* const* d_in, const int* in_sizes, int n_in,
                              void* d_out, int out_size, void* d_ws, size_t ws_size,
                              hipStream_t stream) {
    const float* x  = (const float*)d_in[0];
    const void*  ei = d_in[1];
    const float* W1 = (const float*)d_in[2];
    const float* b1 = (const float*)d_in[3];
    const float* W2 = (const float*)d_in[4];
    const float* b2 = (const float*)d_in[5];

    const int N = N_NODES;
    const int E = in_sizes[1] / 2;

    char* w = (char*)d_ws;
    size_t off = 0;
    auto take = [&](size_t bytes) {
        void* p = w + off;
        off = (off + bytes + 255) & ~(size_t)255;
        return p;
    };
    int*   flag    = (int*)take(2 * sizeof(int));
    int*   tot     = flag + 1;
    int*   cnt     = (int*)take((size_t)N * 4);
    int*   bsumB   = (int*)take(4096 * 4);
    int*   colsum  = (int*)take((size_t)NKEY * 4);
    int*   keybase = (int*)take((size_t)NKEY * 4);
    float* dinv    = (float*)take((size_t)N * 4);
    unsigned* pairs = (unsigned*)take((size_t)E * 4);
    unsigned short* w1bf = (unsigned short*)take(128 * 128 * 2);
    unsigned short* w2bf = (unsigned short*)take(64 * 128 * 2);
    unsigned* hr   = (unsigned*)take((size_t)N * 64 * 4);   // bf16 [N][128] normal order
    unsigned* h2   = (unsigned*)take((size_t)N * 32 * 4);   // bf16 [N][64] interleaved
    (void)ws_size; (void)n_in; (void)out_size;

    // Staging tables ALIAS onto hr/h2 (both dead until after staging):
    //   bhist last read by colprefix_k; hr first written by agg1_k (later).
    //   bbase last read by write1_k;   h2 first written by gemm2_k (later).
    // sizes: NBLK2*NKEY*4 = 10.41MB; hr = 25.6MB, h2 = 12.8MB. Fits.
    int* bhist = (int*)hr;
    int* bbase = (int*)h2;

    unsigned* h1 = (unsigned*)d_out;  // bf16 [N][128] interleaved, dead before agg2 writes

    const int nscanK = (NKEY + 1023) / 1024;   // 10
    const int ngridK = (NKEY + 255) / 256;     // 40

    detect64_k<<<1, 64, 0, stream>>>((const unsigned long long*)ei, flag);
    count1_k<<<NBLK2, 256, 0, stream>>>(ei, flag, bhist, E);
    colsum_k<<<ngridK, 256, 0, stream>>>(bhist, colsum);
    scan1_k<<<nscanK, 256, 0, stream>>>(colsum, keybase, bsumB, NKEY);
    scan2_k<<<1, 256, 0, stream>>>(bsumB, nscanK);
    scanadd_k<<<nscanK, 256, 0, stream>>>(bsumB, keybase, colsum, tot, NKEY);
    colprefix_k<<<ngridK, 256, 0, stream>>>(bhist, keybase, bbase);
    write1_k<<<NBLK2, 256, 0, stream>>>(ei, flag, bbase, pairs, E);
    degree_k<<<NBUCK2, 256, 0, stream>>>(pairs, keybase, tot, cnt, N);
    dinv_k<<<(N + 255) / 256, 256, 0, stream>>>(cnt, dinv, N);
    prep_w_k<<<64, 256, 0, stream>>>(W1, W2, w1bf, w2bf);

    gemm1_k<<<(N + 63) / 64, 256, 0, stream>>>(x, w1bf, dinv, h1, N);
    agg1_k<<<NBUCK2, 512, 128 * 128 * 4, stream>>>(h1, pairs, keybase, tot, dinv, b1, hr, N);
    gemm2_k<<<(N + 63) / 64, 256, 0, stream>>>(hr, w2bf, dinv, h2, N);
    agg2_k<<<NBUCK2, 512, 0, stream>>>(h2, pairs, keybase, tot, dinv, b2, (float*)d_out, N);
}

// Round 6
// 484.591 us; speedup vs baseline: 8.8723x; 8.8636x over previous
//
#include <hip/hip_runtime.h>

// 2-layer GCN, R18: integer fixed-point LDS accumulation.
// R17 falsified the unsafeAtomicAdd fix: counters bit-identical to R16 ->
// unsafeAtomicAdd on a generic pointer does NOT emit ds_add_f32; f32 LDS
// atomicAdd remains a CAS retry loop (~1000 cy/edge, VALU+HBM idle).
// R18: accumulate in int32 fixed-point (x 2^20) using atomicAdd(int*) ->
// native ds_add_u32 (proven fast in count1/write1/degree). Quantization
// ~1e-6/addend, ~70 addends -> <=1e-4, negligible vs 1.95e-3 bf16 absmax.
// Overflow: |h'|<=~8, deg<=~70 -> |sum*2^20| < 0.6e9 << 2^31.
// Everything else identical to R16/R17 (staging, GEMMs, layout, aliasing).

#define N_NODES 100000
#define NBLK2 256          // staging partition blocks
#define NBUCK2 782         // ceil(100000/128) dst buckets of 128
#define NCH 13             // src chunks of 8192 (s>>13)
#define NKEY (NBUCK2 * NCH) // 10166

#define FPS  1048576.0f        // 2^20 fixed-point scale
#define INVS 9.5367431640625e-7f  // 2^-20

typedef __attribute__((ext_vector_type(8))) short short8;
typedef __attribute__((ext_vector_type(4))) float f32x4;

// ---------- bf16 helpers (RN-even) ----------
__device__ __forceinline__ unsigned short f2bf(float f) {
    union { float f; unsigned u; } c; c.f = f;
    unsigned r = (c.u + 0x7fffu + ((c.u >> 16) & 1u)) >> 16;
    return (unsigned short)r;
}
__device__ __forceinline__ float2 bfpair(unsigned u) {
    union { float f; unsigned u; } a, b;
    a.u = u << 16; b.u = u & 0xffff0000u;
    return make_float2(a.f, b.f);
}
__device__ __forceinline__ unsigned packbf(float a, float b) {
    return (unsigned)f2bf(a) | ((unsigned)f2bf(b) << 16);
}
__device__ __forceinline__ int fp20(float v) {
    return __float2int_rn(v * FPS);
}

// ---------- edge dtype detection (one wave) ----------
__global__ void detect64_k(const unsigned long long* __restrict__ ei, int* __restrict__ flag) {
    unsigned long long v = ei[threadIdx.x & 63];
    unsigned long long bad = __ballot(v >= (1ULL << 32));
    if (threadIdx.x == 0) *flag = (bad == 0ULL) ? 1 : 0;
}

__device__ __forceinline__ int edge_at(const void* ei, int is64, long long idx) {
    if (is64) return (int)((const long long*)ei)[idx];
    return ((const int*)ei)[idx];
}

// ---------- pass 1: per-block [bucket x chunk] LDS histogram, block-major out ----------
__global__ __launch_bounds__(256) void count1_k(const void* __restrict__ ei,
                                                const int* __restrict__ flag,
                                                int* __restrict__ bhist, int E) {
    __shared__ int lh[NKEY];
    int t = threadIdx.x;
    for (int i = t; i < NKEY; i += 256) lh[i] = 0;
    __syncthreads();
    int is64 = *flag;
    int C = (E + NBLK2 - 1) / NBLK2;
    int lo = blockIdx.x * C;
    int hi = lo + C; if (hi > E) hi = E;
    for (int e = lo + t; e < hi; e += 256) {
        int s = edge_at(ei, is64, e);
        int d = edge_at(ei, is64, (long long)E + e);
        if ((unsigned)d >= (unsigned)N_NODES) continue;
        if ((unsigned)s >= (unsigned)N_NODES) s = 0;
        atomicAdd(&lh[(d >> 7) * NCH + (s >> 13)], 1);
    }
    __syncthreads();
    int* dst = bhist + (size_t)blockIdx.x * NKEY;   // block-major: coalesced
    for (int i = t; i < NKEY; i += 256) dst[i] = lh[i];
}

// ---------- column sums over partitions (coalesced across keys) ----------
__global__ void colsum_k(const int* __restrict__ bhist, int* __restrict__ colsum) {
    int k = blockIdx.x * 256 + threadIdx.x;
    if (k >= NKEY) return;
    int s = 0;
#pragma unroll 4
    for (int b = 0; b < NBLK2; ++b) s += bhist[(size_t)b * NKEY + k];
    colsum[k] = s;
}

// ---------- generic exclusive scan, 1024 elems/block ----------
__global__ void scan1_k(const int* __restrict__ cnt, int* __restrict__ partial,
                        int* __restrict__ bsum, int n) {
    __shared__ int sm[256];
    int t = threadIdx.x;
    int base = blockIdx.x * 1024 + t * 4;
    int v[4]; int loc = 0;
#pragma unroll
    for (int j = 0; j < 4; ++j) { v[j] = (base + j < n) ? cnt[base + j] : 0; loc += v[j]; }
    sm[t] = loc; __syncthreads();
    for (int off = 1; off < 256; off <<= 1) {
        int x = (t >= off) ? sm[t - off] : 0;
        __syncthreads();
        sm[t] += x;
        __syncthreads();
    }
    int incl = sm[t];
    int run = incl - loc;
    if (t == 255) bsum[blockIdx.x] = incl;
#pragma unroll
    for (int j = 0; j < 4; ++j) {
        if (base + j < n) partial[base + j] = run;
        run += v[j];
    }
}

// exclusive scan of block sums in place (16 per thread, up to 4096)
__global__ void scan2_k(int* __restrict__ bsum, int nb) {
    __shared__ int sm[256];
    int t = threadIdx.x;
    int v[16]; int loc = 0;
#pragma unroll
    for (int i = 0; i < 16; ++i) {
        int idx = t * 16 + i;
        v[i] = (idx < nb) ? bsum[idx] : 0;
        loc += v[i];
    }
    sm[t] = loc; __syncthreads();
    for (int off = 1; off < 256; off <<= 1) {
        int x = (t >= off) ? sm[t - off] : 0;
        __syncthreads();
        sm[t] += x;
        __syncthreads();
    }
    int run = sm[t] - loc;
#pragma unroll
    for (int i = 0; i < 16; ++i) {
        int idx = t * 16 + i;
        if (idx < nb) bsum[idx] = run;
        run += v[i];
    }
}

// finalize key-base scan in place; also emit total valid count
__global__ void scanadd_k(const int* __restrict__ bsum, int* __restrict__ arr,
                          const int* __restrict__ raw, int* __restrict__ tot, int n) {
    int base = blockIdx.x * 1024 + threadIdx.x * 4;
    int add = bsum[blockIdx.x];
#pragma unroll
    for (int j = 0; j < 4; ++j) {
        int i = base + j;
        if (i < n) {
            int v = arr[i] + add;
            arr[i] = v;
            if (i == n - 1) *tot = v + raw[i];
        }
    }
}

// per-(blk,key) base = keybase[key] + prefix over partitions (coalesced)
__global__ void colprefix_k(const int* __restrict__ bhist, const int* __restrict__ keybase,
                            int* __restrict__ bbase) {
    int k = blockIdx.x * 256 + threadIdx.x;
    if (k >= NKEY) return;
    int run = keybase[k];
#pragma unroll 8
    for (int b = 0; b < NBLK2; ++b) {
        size_t i = (size_t)b * NKEY + k;
        int c = bhist[i];
        bbase[i] = run;
        run += c;
    }
}

// dinv straight from degree
__global__ void dinv_k(const int* __restrict__ cnt, float* __restrict__ dinv, int n) {
    int i = blockIdx.x * 256 + threadIdx.x;
    if (i < n) dinv[i] = rsqrtf((float)(cnt[i] + 1));  // +1 self-loop
}

// ---------- pass 2: staging write sorted by (bucket, chunk) ----------
__global__ __launch_bounds__(256) void write1_k(const void* __restrict__ ei,
                                                const int* __restrict__ flag,
                                                const int* __restrict__ bbase,
                                                unsigned* __restrict__ pairs, int E) {
    __shared__ int lofs[NKEY];
    int t = threadIdx.x;
    const int* src0 = bbase + (size_t)blockIdx.x * NKEY;
    for (int i = t; i < NKEY; i += 256) lofs[i] = src0[i];
    __syncthreads();
    int is64 = *flag;
    int C = (E + NBLK2 - 1) / NBLK2;
    int lo = blockIdx.x * C;
    int hi = lo + C; if (hi > E) hi = E;
    for (int e = lo + t; e < hi; e += 256) {
        int s = edge_at(ei, is64, e);
        int d = edge_at(ei, is64, (long long)E + e);
        if ((unsigned)d >= (unsigned)N_NODES) continue;
        if ((unsigned)s >= (unsigned)N_NODES) s = 0;
        int key = (d >> 7) * NCH + (s >> 13);
        int p = atomicAdd(&lofs[key], 1);
        pairs[p] = (unsigned)s | ((unsigned)(d & 127) << 17);
    }
}

// ---------- degrees from staged pairs: one block per bucket ----------
__global__ __launch_bounds__(256) void degree_k(const unsigned* __restrict__ pairs,
                                                const int* __restrict__ keybase,
                                                const int* __restrict__ tot,
                                                int* __restrict__ cnt, int Nn) {
    __shared__ int lh[128];
    int b = blockIdx.x;
    int t = threadIdx.x;
    if (t < 128) lh[t] = 0;
    __syncthreads();
    int lo = keybase[b * NCH];
    int hi = (b == NBUCK2 - 1) ? *tot : keybase[(b + 1) * NCH];
    for (int i = lo + t; i < hi; i += 256) {
        unsigned p = __builtin_nontemporal_load(pairs + i);
        atomicAdd(&lh[p >> 17], 1);
    }
    __syncthreads();
    int n0 = b << 7;
    if (t < 128 && n0 + t < Nn) cnt[n0 + t] = lh[t];
}

// ---------- weight prep: W^T in bf16 ----------
__global__ void prep_w_k(const float* __restrict__ W1, const float* __restrict__ W2,
                         unsigned short* __restrict__ w1bf, unsigned short* __restrict__ w2bf) {
    int i = blockIdx.x * 256 + threadIdx.x;
    if (i < 128 * 128) { int k = i >> 7, f = i & 127; w1bf[f * 128 + k] = f2bf(W1[i]); }
    if (i < 128 * 64)  { int k = i >> 6, f = i & 63;  w2bf[f * 128 + k] = f2bf(W2[i]); }
}

// ---------- GEMM1 (MFMA): h1[n] = dinv[n]*(x @ W1), feature-interleaved ----------
// h1[n][q] u32 = bf(feat q) | bf(feat q+64) << 16, q < 64
__global__ __launch_bounds__(256) void gemm1_k(const float* __restrict__ x,
                                               const unsigned short* __restrict__ w1bf,
                                               const float* __restrict__ dinv,
                                               unsigned* __restrict__ h1, int Nn) {
    __shared__ __align__(16) unsigned short sA[128][136];  // W1^T [feat][k]
    __shared__ __align__(16) unsigned short sB[64][136];   // x [node][k] bf16
    int tid = threadIdx.x;
    int n0g = blockIdx.x * 64;
    {
        const uint4* src = (const uint4*)w1bf;
#pragma unroll
        for (int l = 0; l < 8; ++l) {
            int idx = tid + l * 256;
            int f = idx >> 4, kq = idx & 15;
            *(uint4*)&sA[f][kq * 8] = src[idx];
        }
    }
    {
        int n = tid >> 2, kq = tid & 3;
        int gn = n0g + n; if (gn >= Nn) gn = Nn - 1;
        const float4* xr = (const float4*)(x + (size_t)gn * 128 + kq * 32);
        unsigned short* dst = &sB[n][kq * 32];
#pragma unroll
        for (int i = 0; i < 8; ++i) {
            float4 v = xr[i];
            dst[i * 4 + 0] = f2bf(v.x); dst[i * 4 + 1] = f2bf(v.y);
            dst[i * 4 + 2] = f2bf(v.z); dst[i * 4 + 3] = f2bf(v.w);
        }
    }
    __syncthreads();
    int wave = tid >> 6, lane = tid & 63;
    int quad = lane >> 4, l16 = lane & 15;
    f32x4 z = {0.f, 0.f, 0.f, 0.f};
    f32x4 acc[8];
#pragma unroll
    for (int t = 0; t < 8; ++t) acc[t] = z;
#pragma unroll
    for (int kk = 0; kk < 4; ++kk) {
        int kb = kk * 32 + quad * 8;
        short8 a = *(const short8*)&sB[wave * 16 + l16][kb];
#pragma unroll
        for (int ft = 0; ft < 8; ++ft) {
            short8 b = *(const short8*)&sA[ft * 16 + l16][kb];
            acc[ft] = __builtin_amdgcn_mfma_f32_16x16x32_bf16(a, b, acc[ft], 0, 0, 0);
        }
    }
    float dv[4];
#pragma unroll
    for (int r = 0; r < 4; ++r) {
        int gn = n0g + wave * 16 + quad * 4 + r;
        if (gn >= Nn) gn = Nn - 1;
        dv[r] = dinv[gn];
    }
    __syncthreads();  // reuse sA as transpose buffer
    unsigned short (*sC)[136] = sA;
#pragma unroll
    for (int ft = 0; ft < 8; ++ft)
#pragma unroll
        for (int r = 0; r < 4; ++r)
            sC[wave * 16 + quad * 4 + r][ft * 16 + l16] = f2bf(dv[r] * acc[ft][r]);
    __syncthreads();
#pragma unroll
    for (int l = 0; l < 4; ++l) {
        int idx = tid + l * 256;
        int row = idx >> 4, g = idx & 15;
        int gn = n0g + row;
        if (gn < Nn) {
            ushort4 A = *(ushort4*)&sC[row][g * 4];
            ushort4 B = *(ushort4*)&sC[row][g * 4 + 64];
            uint4 o;
            o.x = (unsigned)A.x | ((unsigned)B.x << 16);
            o.y = (unsigned)A.y | ((unsigned)B.y << 16);
            o.z = (unsigned)A.z | ((unsigned)B.z << 16);
            o.w = (unsigned)A.w | ((unsigned)B.w << 16);
            *(uint4*)&h1[(size_t)gn * 64 + g * 4] = o;
        }
    }
}

// ---------- GEMM2 (MFMA): h2[n] = dinv[n]*(hr @ W2), feature-interleaved ----------
// h2[n][q] u32 = bf(feat q) | bf(feat q+32) << 16, q < 32
__global__ __launch_bounds__(256) void gemm2_k(const unsigned* __restrict__ hr,
                                               const unsigned short* __restrict__ w2bf,
                                               const float* __restrict__ dinv,
                                               unsigned* __restrict__ h2, int Nn) {
    __shared__ __align__(16) unsigned short sA[64][136];
    __shared__ __align__(16) unsigned short sB[64][136];
    int tid = threadIdx.x;
    int n0g = blockIdx.x * 64;
    {
        const uint4* src = (const uint4*)w2bf;
#pragma unroll
        for (int l = 0; l < 4; ++l) {
            int idx = tid + l * 256;
            int f = idx >> 4, kq = idx & 15;
            *(uint4*)&sA[f][kq * 8] = src[idx];
        }
    }
    {
        const uint4* src = (const uint4*)hr;
#pragma unroll
        for (int l = 0; l < 4; ++l) {
            int idx = tid + l * 256;
            int row = idx >> 4, q = idx & 15;
            int gn = n0g + row; if (gn >= Nn) gn = Nn - 1;
            *(uint4*)&sB[row][q * 8] = src[(size_t)gn * 16 + q];
        }
    }
    __syncthreads();
    int wave = tid >> 6, lane = tid & 63;
    int quad = lane >> 4, l16 = lane & 15;
    f32x4 z = {0.f, 0.f, 0.f, 0.f};
    f32x4 acc[4];
#pragma unroll
    for (int t = 0; t < 4; ++t) acc[t] = z;
#pragma unroll
    for (int kk = 0; kk < 4; ++kk) {
        int kb = kk * 32 + quad * 8;
        short8 a = *(const short8*)&sB[wave * 16 + l16][kb];
#pragma unroll
        for (int ft = 0; ft < 4; ++ft) {
            short8 b = *(const short8*)&sA[ft * 16 + l16][kb];
            acc[ft] = __builtin_amdgcn_mfma_f32_16x16x32_bf16(a, b, acc[ft], 0, 0, 0);
        }
    }
    float dv[4];
#pragma unroll
    for (int r = 0; r < 4; ++r) {
        int gn = n0g + wave * 16 + quad * 4 + r;
        if (gn >= Nn) gn = Nn - 1;
        dv[r] = dinv[gn];
    }
    __syncthreads();
    unsigned short (*sC)[136] = sA;
#pragma unroll
    for (int ft = 0; ft < 4; ++ft)
#pragma unroll
        for (int r = 0; r < 4; ++r)
            sC[wave * 16 + quad * 4 + r][ft * 16 + l16] = f2bf(dv[r] * acc[ft][r]);
    __syncthreads();
#pragma unroll
    for (int l = 0; l < 2; ++l) {
        int idx = tid + l * 256;
        int row = idx >> 3, g = idx & 7;
        int gn = n0g + row;
        if (gn < Nn) {
            ushort4 A = *(ushort4*)&sC[row][g * 4];
            ushort4 B = *(ushort4*)&sC[row][g * 4 + 32];
            uint4 o;
            o.x = (unsigned)A.x | ((unsigned)B.x << 16);
            o.y = (unsigned)A.y | ((unsigned)B.y << 16);
            o.z = (unsigned)A.z | ((unsigned)B.z << 16);
            o.w = (unsigned)A.w | ((unsigned)B.w << 16);
            *(uint4*)&h2[(size_t)gn * 32 + g * 4] = o;
        }
    }
}

// ---------- agg1: block=bucket(128 dst), int32 fixed-point LDS accum ----------
// out[dst] = relu( di * (sum h'[src] + h'[self]) + b ), out packed bf16
__global__ __launch_bounds__(512) void agg1_k(const unsigned* __restrict__ h,
                                              const unsigned* __restrict__ pairs,
                                              const int* __restrict__ keybase,
                                              const int* __restrict__ tot,
                                              const float* __restrict__ dinv,
                                              const float* __restrict__ bias,
                                              unsigned* __restrict__ out, int Nn) {
    extern __shared__ int iacc[];   // [128][128] fixed-point 2^20
    int tid = threadIdx.x, lane = tid & 63, wave = tid >> 6;
    int b = blockIdx.x, n0 = b << 7;
    // init with self rows (h already dinv-prescaled; interleaved (q, q+64))
    for (int i = tid; i < 128 * 64; i += 512) {
        int row = i >> 6, q = i & 63;
        unsigned u = (n0 + row < Nn) ? h[(size_t)(n0 + row) * 64 + q] : 0u;
        float2 v = bfpair(u);
        iacc[row * 128 + q] = fp20(v.x);
        iacc[row * 128 + 64 + q] = fp20(v.y);
    }
    __syncthreads();
    int lo = keybase[b * NCH];
    int hi = (b == NBUCK2 - 1) ? *tot : keybase[(b + 1) * NCH];
    for (int base = lo + wave * 64; base < hi; base += 512) {
        int idx = base + lane;
        unsigned pv = pairs[(idx < hi) ? idx : (hi - 1)];
        int m = hi - base; if (m > 64) m = 64;
        int j = 0;
        for (; j + 4 <= m; j += 4) {
            unsigned p0 = __shfl(pv, j),     p1 = __shfl(pv, j + 1);
            unsigned p2 = __shfl(pv, j + 2), p3 = __shfl(pv, j + 3);
            unsigned u0 = h[((p0 & 0x1FFFFu) << 6) + lane];
            unsigned u1 = h[((p1 & 0x1FFFFu) << 6) + lane];
            unsigned u2 = h[((p2 & 0x1FFFFu) << 6) + lane];
            unsigned u3 = h[((p3 & 0x1FFFFu) << 6) + lane];
            float2 v0 = bfpair(u0); int* a0 = &iacc[((p0 >> 17) << 7) + lane];
            atomicAdd(a0, fp20(v0.x)); atomicAdd(a0 + 64, fp20(v0.y));
            float2 v1 = bfpair(u1); int* a1 = &iacc[((p1 >> 17) << 7) + lane];
            atomicAdd(a1, fp20(v1.x)); atomicAdd(a1 + 64, fp20(v1.y));
            float2 v2 = bfpair(u2); int* a2 = &iacc[((p2 >> 17) << 7) + lane];
            atomicAdd(a2, fp20(v2.x)); atomicAdd(a2 + 64, fp20(v2.y));
            float2 v3 = bfpair(u3); int* a3 = &iacc[((p3 >> 17) << 7) + lane];
            atomicAdd(a3, fp20(v3.x)); atomicAdd(a3 + 64, fp20(v3.y));
        }
        for (; j < m; ++j) {
            unsigned p = __shfl(pv, j);
            unsigned u = h[((p & 0x1FFFFu) << 6) + lane];
            float2 v = bfpair(u);
            int* a = &iacc[((p >> 17) << 7) + lane];
            atomicAdd(a, fp20(v.x)); atomicAdd(a + 64, fp20(v.y));
        }
    }
    __syncthreads();
    int nn = Nn - n0; if (nn > 128) nn = 128;
    for (int i = tid; i < nn * 64; i += 512) {
        int row = i >> 6, q = i & 63;
        float di = dinv[n0 + row];
        float sx = (float)iacc[row * 128 + 2 * q] * INVS;
        float sy = (float)iacc[row * 128 + 2 * q + 1] * INVS;
        float r0 = fmaxf(fmaf(di, sx, bias[2 * q]), 0.f);
        float r1 = fmaxf(fmaf(di, sy, bias[2 * q + 1]), 0.f);
        out[(size_t)(n0 + row) * 64 + q] = packbf(r0, r1);
    }
}

// ---------- agg2: block=bucket(128 dst), 32KB int32 LDS accum ----------
__global__ __launch_bounds__(512) void agg2_k(const unsigned* __restrict__ h,
                                              const unsigned* __restrict__ pairs,
                                              const int* __restrict__ keybase,
                                              const int* __restrict__ tot,
                                              const float* __restrict__ dinv,
                                              const float* __restrict__ bias,
                                              float* __restrict__ out, int Nn) {
    __shared__ int iacc[128 * 64];
    int tid = threadIdx.x, lane = tid & 63, wave = tid >> 6;
    int half = lane >> 5, fl = lane & 31;
    int b = blockIdx.x, n0 = b << 7;
    for (int i = tid; i < 128 * 32; i += 512) {
        int row = i >> 5, q = i & 31;
        unsigned u = (n0 + row < Nn) ? h[(size_t)(n0 + row) * 32 + q] : 0u;
        float2 v = bfpair(u);
        iacc[row * 64 + q] = fp20(v.x);
        iacc[row * 64 + 32 + q] = fp20(v.y);
    }
    __syncthreads();
    int lo = keybase[b * NCH];
    int hi = (b == NBUCK2 - 1) ? *tot : keybase[(b + 1) * NCH];
    for (int base = lo + wave * 64; base < hi; base += 512) {
        int idx = base + lane;
        unsigned pv = pairs[(idx < hi) ? idx : (hi - 1)];
        int m = hi - base; if (m > 64) m = 64;
        int j = 0;
        for (; j + 8 <= m; j += 8) {
            unsigned p0 = __shfl(pv, j + half);
            unsigned p1 = __shfl(pv, j + 2 + half);
            unsigned p2 = __shfl(pv, j + 4 + half);
            unsigned p3 = __shfl(pv, j + 6 + half);
            unsigned u0 = h[((p0 & 0x1FFFFu) << 5) + fl];
            unsigned u1 = h[((p1 & 0x1FFFFu) << 5) + fl];
            unsigned u2 = h[((p2 & 0x1FFFFu) << 5) + fl];
            unsigned u3 = h[((p3 & 0x1FFFFu) << 5) + fl];
            float2 v0 = bfpair(u0); int* a0 = &iacc[((p0 >> 17) << 6) + fl];
            atomicAdd(a0, fp20(v0.x)); atomicAdd(a0 + 32, fp20(v0.y));
            float2 v1 = bfpair(u1); int* a1 = &iacc[((p1 >> 17) << 6) + fl];
            atomicAdd(a1, fp20(v1.x)); atomicAdd(a1 + 32, fp20(v1.y));
            float2 v2 = bfpair(u2); int* a2 = &iacc[((p2 >> 17) << 6) + fl];
            atomicAdd(a2, fp20(v2.x)); atomicAdd(a2 + 32, fp20(v2.y));
            float2 v3 = bfpair(u3); int* a3 = &iacc[((p3 >> 17) << 6) + fl];
            atomicAdd(a3, fp20(v3.x)); atomicAdd(a3 + 32, fp20(v3.y));
        }
        for (; j < m; j += 2) {
            int q = j + half;
            unsigned p = __shfl(pv, (q < m) ? q : j);
            if (q < m) {
                unsigned u = h[((p & 0x1FFFFu) << 5) + fl];
                float2 v = bfpair(u);
                int* a = &iacc[((p >> 17) << 6) + fl];
                atomicAdd(a, fp20(v.x)); atomicAdd(a + 32, fp20(v.y));
            }
        }
    }
    __syncthreads();
    int nn = Nn - n0; if (nn > 128) nn = 128;
    for (int i = tid; i < nn * 64; i += 512) {
        int row = i >> 6, f = i & 63;
        float di = dinv[n0 + row];
        float s = (float)iacc[row * 64 + f] * INVS;
        out[(size_t)(n0 + row) * 64 + f] = fmaf(di, s, bias[f]);
    }
}

// ---------- launch ----------
extern "C" void kernel_launch(void* const* d_in, const int* in_sizes, int n_in,
                              void* d_out, int out_size, void* d_ws, size_t ws_size,
                              hipStream_t stream) {
    const float* x  = (const float*)d_in[0];
    const void*  ei = d_in[1];
    const float* W1 = (const float*)d_in[2];
    const float* b1 = (const float*)d_in[3];
    const float* W2 = (const float*)d_in[4];
    const float* b2 = (const float*)d_in[5];

    const int N = N_NODES;
    const int E = in_sizes[1] / 2;

    char* w = (char*)d_ws;
    size_t off = 0;
    auto take = [&](size_t bytes) {
        void* p = w + off;
        off = (off + bytes + 255) & ~(size_t)255;
        return p;
    };
    int*   flag    = (int*)take(2 * sizeof(int));
    int*   tot     = flag + 1;
    int*   cnt     = (int*)take((size_t)N * 4);
    int*   bsumB   = (int*)take(4096 * 4);
    int*   colsum  = (int*)take((size_t)NKEY * 4);
    int*   keybase = (int*)take((size_t)NKEY * 4);
    float* dinv    = (float*)take((size_t)N * 4);
    unsigned* pairs = (unsigned*)take((size_t)E * 4);
    unsigned short* w1bf = (unsigned short*)take(128 * 128 * 2);
    unsigned short* w2bf = (unsigned short*)take(64 * 128 * 2);
    unsigned* hr   = (unsigned*)take((size_t)N * 64 * 4);   // bf16 [N][128] normal order
    unsigned* h2   = (unsigned*)take((size_t)N * 32 * 4);   // bf16 [N][64] interleaved
    (void)ws_size; (void)n_in; (void)out_size;

    // Staging tables ALIAS onto hr/h2 (both dead until after staging):
    //   bhist last read by colprefix_k; hr first written by agg1_k (later).
    //   bbase last read by write1_k;   h2 first written by gemm2_k (later).
    int* bhist = (int*)hr;
    int* bbase = (int*)h2;

    unsigned* h1 = (unsigned*)d_out;  // bf16 [N][128] interleaved, dead before agg2 writes

    const int nscanK = (NKEY + 1023) / 1024;   // 10
    const int ngridK = (NKEY + 255) / 256;     // 40

    detect64_k<<<1, 64, 0, stream>>>((const unsigned long long*)ei, flag);
    count1_k<<<NBLK2, 256, 0, stream>>>(ei, flag, bhist, E);
    colsum_k<<<ngridK, 256, 0, stream>>>(bhist, colsum);
    scan1_k<<<nscanK, 256, 0, stream>>>(colsum, keybase, bsumB, NKEY);
    scan2_k<<<1, 256, 0, stream>>>(bsumB, nscanK);
    scanadd_k<<<nscanK, 256, 0, stream>>>(bsumB, keybase, colsum, tot, NKEY);
    colprefix_k<<<ngridK, 256, 0, stream>>>(bhist, keybase, bbase);
    write1_k<<<NBLK2, 256, 0, stream>>>(ei, flag, bbase, pairs, E);
    degree_k<<<NBUCK2, 256, 0, stream>>>(pairs, keybase, tot, cnt, N);
    dinv_k<<<(N + 255) / 256, 256, 0, stream>>>(cnt, dinv, N);
    prep_w_k<<<64, 256, 0, stream>>>(W1, W2, w1bf, w2bf);

    gemm1_k<<<(N + 63) / 64, 256, 0, stream>>>(x, w1bf, dinv, h1, N);
    agg1_k<<<NBUCK2, 512, 128 * 128 * 4, stream>>>(h1, pairs, keybase, tot, dinv, b1, hr, N);
    gemm2_k<<<(N + 63) / 64, 256, 0, stream>>>(hr, w2bf, dinv, h2, N);
    agg2_k<<<NBUCK2, 512, 0, stream>>>(h2, pairs, keybase, tot, dinv, b2, (float*)d_out, N);
}

// Round 7
// 441.062 us; speedup vs baseline: 9.7479x; 1.0987x over previous
//
#include <hip/hip_runtime.h>

// 2-layer GCN, R19: s16 fixed-point h tables + 1024-thread agg blocks.
// R18 post-mortem: int LDS atomics fixed the CAS collapse (2715->180us,
// theory confirmed). Remaining: VALUBusy 47.6% @ occupancy 32% -- per-edge
// f32->fixed conversion (~8 extra VALU/edge) is the bottleneck, occupancy
// capped at 16 waves/CU (64KB LDS x 512thr). R19:
// (a) GEMM epilogues emit h directly as s16 fixed-point (x 2^13, saturated
//     +-32767): edge loop = gather u32, 2 sign-extracts, 2 ds_add. s16 step
//     1.2e-4 is FINER than the bf16 it replaces; range +-4 safe (|h'|<=~2).
// (b) agg1/agg2 use 1024-thread blocks: 2 blocks/CU x 16 waves = 32 waves/CU
//     (100% occupancy cap vs 50%), smoother 1.53-round tail.
// Staging/scans/GEMM cores unchanged from R18 (FETCH 210MB = exact
// first-touch: the chunk-sort works; don't touch it).

#define N_NODES 100000
#define NBLK2 256          // staging partition blocks
#define NBUCK2 782         // ceil(100000/128) dst buckets of 128
#define NCH 13             // src chunks of 8192 (s>>13)
#define NKEY (NBUCK2 * NCH) // 10166

#define QS   8192.0f           // 2^13 fixed-point scale
#define IQS  1.220703125e-4f   // 2^-13

typedef __attribute__((ext_vector_type(8))) short short8;
typedef __attribute__((ext_vector_type(4))) float f32x4;

// ---------- bf16 helpers (RN-even) ----------
__device__ __forceinline__ unsigned short f2bf(float f) {
    union { float f; unsigned u; } c; c.f = f;
    unsigned r = (c.u + 0x7fffu + ((c.u >> 16) & 1u)) >> 16;
    return (unsigned short)r;
}
__device__ __forceinline__ unsigned packbf(float a, float b) {
    return (unsigned)f2bf(a) | ((unsigned)f2bf(b) << 16);
}
// f32 -> saturated s16 fixed point (x 2^13), returned as raw bit pattern
__device__ __forceinline__ unsigned short q13(float v) {
    int i = __float2int_rn(v * QS);
    i = i < -32767 ? -32767 : (i > 32767 ? 32767 : i);
    return (unsigned short)(i & 0xffff);
}

// ---------- edge dtype detection (one wave) ----------
__global__ void detect64_k(const unsigned long long* __restrict__ ei, int* __restrict__ flag) {
    unsigned long long v = ei[threadIdx.x & 63];
    unsigned long long bad = __ballot(v >= (1ULL << 32));
    if (threadIdx.x == 0) *flag = (bad == 0ULL) ? 1 : 0;
}

__device__ __forceinline__ int edge_at(const void* ei, int is64, long long idx) {
    if (is64) return (int)((const long long*)ei)[idx];
    return ((const int*)ei)[idx];
}

// ---------- pass 1: per-block [bucket x chunk] LDS histogram, block-major out ----------
__global__ __launch_bounds__(256) void count1_k(const void* __restrict__ ei,
                                                const int* __restrict__ flag,
                                                int* __restrict__ bhist, int E) {
    __shared__ int lh[NKEY];
    int t = threadIdx.x;
    for (int i = t; i < NKEY; i += 256) lh[i] = 0;
    __syncthreads();
    int is64 = *flag;
    int C = (E + NBLK2 - 1) / NBLK2;
    int lo = blockIdx.x * C;
    int hi = lo + C; if (hi > E) hi = E;
    for (int e = lo + t; e < hi; e += 256) {
        int s = edge_at(ei, is64, e);
        int d = edge_at(ei, is64, (long long)E + e);
        if ((unsigned)d >= (unsigned)N_NODES) continue;
        if ((unsigned)s >= (unsigned)N_NODES) s = 0;
        atomicAdd(&lh[(d >> 7) * NCH + (s >> 13)], 1);
    }
    __syncthreads();
    int* dst = bhist + (size_t)blockIdx.x * NKEY;   // block-major: coalesced
    for (int i = t; i < NKEY; i += 256) dst[i] = lh[i];
}

// ---------- column sums over partitions (coalesced across keys) ----------
__global__ void colsum_k(const int* __restrict__ bhist, int* __restrict__ colsum) {
    int k = blockIdx.x * 256 + threadIdx.x;
    if (k >= NKEY) return;
    int s = 0;
#pragma unroll 4
    for (int b = 0; b < NBLK2; ++b) s += bhist[(size_t)b * NKEY + k];
    colsum[k] = s;
}

// ---------- generic exclusive scan, 1024 elems/block ----------
__global__ void scan1_k(const int* __restrict__ cnt, int* __restrict__ partial,
                        int* __restrict__ bsum, int n) {
    __shared__ int sm[256];
    int t = threadIdx.x;
    int base = blockIdx.x * 1024 + t * 4;
    int v[4]; int loc = 0;
#pragma unroll
    for (int j = 0; j < 4; ++j) { v[j] = (base + j < n) ? cnt[base + j] : 0; loc += v[j]; }
    sm[t] = loc; __syncthreads();
    for (int off = 1; off < 256; off <<= 1) {
        int x = (t >= off) ? sm[t - off] : 0;
        __syncthreads();
        sm[t] += x;
        __syncthreads();
    }
    int incl = sm[t];
    int run = incl - loc;
    if (t == 255) bsum[blockIdx.x] = incl;
#pragma unroll
    for (int j = 0; j < 4; ++j) {
        if (base + j < n) partial[base + j] = run;
        run += v[j];
    }
}

// exclusive scan of block sums in place (16 per thread, up to 4096)
__global__ void scan2_k(int* __restrict__ bsum, int nb) {
    __shared__ int sm[256];
    int t = threadIdx.x;
    int v[16]; int loc = 0;
#pragma unroll
    for (int i = 0; i < 16; ++i) {
        int idx = t * 16 + i;
        v[i] = (idx < nb) ? bsum[idx] : 0;
        loc += v[i];
    }
    sm[t] = loc; __syncthreads();
    for (int off = 1; off < 256; off <<= 1) {
        int x = (t >= off) ? sm[t - off] : 0;
        __syncthreads();
        sm[t] += x;
        __syncthreads();
    }
    int run = sm[t] - loc;
#pragma unroll
    for (int i = 0; i < 16; ++i) {
        int idx = t * 16 + i;
        if (idx < nb) bsum[idx] = run;
        run += v[i];
    }
}

// finalize key-base scan in place; also emit total valid count
__global__ void scanadd_k(const int* __restrict__ bsum, int* __restrict__ arr,
                          const int* __restrict__ raw, int* __restrict__ tot, int n) {
    int base = blockIdx.x * 1024 + threadIdx.x * 4;
    int add = bsum[blockIdx.x];
#pragma unroll
    for (int j = 0; j < 4; ++j) {
        int i = base + j;
        if (i < n) {
            int v = arr[i] + add;
            arr[i] = v;
            if (i == n - 1) *tot = v + raw[i];
        }
    }
}

// per-(blk,key) base = keybase[key] + prefix over partitions (coalesced)
__global__ void colprefix_k(const int* __restrict__ bhist, const int* __restrict__ keybase,
                            int* __restrict__ bbase) {
    int k = blockIdx.x * 256 + threadIdx.x;
    if (k >= NKEY) return;
    int run = keybase[k];
#pragma unroll 8
    for (int b = 0; b < NBLK2; ++b) {
        size_t i = (size_t)b * NKEY + k;
        int c = bhist[i];
        bbase[i] = run;
        run += c;
    }
}

// dinv straight from degree
__global__ void dinv_k(const int* __restrict__ cnt, float* __restrict__ dinv, int n) {
    int i = blockIdx.x * 256 + threadIdx.x;
    if (i < n) dinv[i] = rsqrtf((float)(cnt[i] + 1));  // +1 self-loop
}

// ---------- pass 2: staging write sorted by (bucket, chunk) ----------
__global__ __launch_bounds__(256) void write1_k(const void* __restrict__ ei,
                                                const int* __restrict__ flag,
                                                const int* __restrict__ bbase,
                                                unsigned* __restrict__ pairs, int E) {
    __shared__ int lofs[NKEY];
    int t = threadIdx.x;
    const int* src0 = bbase + (size_t)blockIdx.x * NKEY;
    for (int i = t; i < NKEY; i += 256) lofs[i] = src0[i];
    __syncthreads();
    int is64 = *flag;
    int C = (E + NBLK2 - 1) / NBLK2;
    int lo = blockIdx.x * C;
    int hi = lo + C; if (hi > E) hi = E;
    for (int e = lo + t; e < hi; e += 256) {
        int s = edge_at(ei, is64, e);
        int d = edge_at(ei, is64, (long long)E + e);
        if ((unsigned)d >= (unsigned)N_NODES) continue;
        if ((unsigned)s >= (unsigned)N_NODES) s = 0;
        int key = (d >> 7) * NCH + (s >> 13);
        int p = atomicAdd(&lofs[key], 1);
        pairs[p] = (unsigned)s | ((unsigned)(d & 127) << 17);
    }
}

// ---------- degrees from staged pairs: one block per bucket ----------
__global__ __launch_bounds__(256) void degree_k(const unsigned* __restrict__ pairs,
                                                const int* __restrict__ keybase,
                                                const int* __restrict__ tot,
                                                int* __restrict__ cnt, int Nn) {
    __shared__ int lh[128];
    int b = blockIdx.x;
    int t = threadIdx.x;
    if (t < 128) lh[t] = 0;
    __syncthreads();
    int lo = keybase[b * NCH];
    int hi = (b == NBUCK2 - 1) ? *tot : keybase[(b + 1) * NCH];
    for (int i = lo + t; i < hi; i += 256) {
        unsigned p = __builtin_nontemporal_load(pairs + i);
        atomicAdd(&lh[p >> 17], 1);
    }
    __syncthreads();
    int n0 = b << 7;
    if (t < 128 && n0 + t < Nn) cnt[n0 + t] = lh[t];
}

// ---------- weight prep: W^T in bf16 ----------
__global__ void prep_w_k(const float* __restrict__ W1, const float* __restrict__ W2,
                         unsigned short* __restrict__ w1bf, unsigned short* __restrict__ w2bf) {
    int i = blockIdx.x * 256 + threadIdx.x;
    if (i < 128 * 128) { int k = i >> 7, f = i & 127; w1bf[f * 128 + k] = f2bf(W1[i]); }
    if (i < 128 * 64)  { int k = i >> 6, f = i & 63;  w2bf[f * 128 + k] = f2bf(W2[i]); }
}

// ---------- GEMM1 (MFMA): h1[n] = dinv[n]*(x @ W1), s16 fixed interleaved ----------
// h1[n][q] u32 = s16(feat q) | s16(feat q+64) << 16, q < 64; scale 2^13
__global__ __launch_bounds__(256) void gemm1_k(const float* __restrict__ x,
                                               const unsigned short* __restrict__ w1bf,
                                               const float* __restrict__ dinv,
                                               unsigned* __restrict__ h1, int Nn) {
    __shared__ __align__(16) unsigned short sA[128][136];  // W1^T [feat][k]
    __shared__ __align__(16) unsigned short sB[64][136];   // x [node][k] bf16
    int tid = threadIdx.x;
    int n0g = blockIdx.x * 64;
    {
        const uint4* src = (const uint4*)w1bf;
#pragma unroll
        for (int l = 0; l < 8; ++l) {
            int idx = tid + l * 256;
            int f = idx >> 4, kq = idx & 15;
            *(uint4*)&sA[f][kq * 8] = src[idx];
        }
    }
    {
        int n = tid >> 2, kq = tid & 3;
        int gn = n0g + n; if (gn >= Nn) gn = Nn - 1;
        const float4* xr = (const float4*)(x + (size_t)gn * 128 + kq * 32);
        unsigned short* dst = &sB[n][kq * 32];
#pragma unroll
        for (int i = 0; i < 8; ++i) {
            float4 v = xr[i];
            dst[i * 4 + 0] = f2bf(v.x); dst[i * 4 + 1] = f2bf(v.y);
            dst[i * 4 + 2] = f2bf(v.z); dst[i * 4 + 3] = f2bf(v.w);
        }
    }
    __syncthreads();
    int wave = tid >> 6, lane = tid & 63;
    int quad = lane >> 4, l16 = lane & 15;
    f32x4 z = {0.f, 0.f, 0.f, 0.f};
    f32x4 acc[8];
#pragma unroll
    for (int t = 0; t < 8; ++t) acc[t] = z;
#pragma unroll
    for (int kk = 0; kk < 4; ++kk) {
        int kb = kk * 32 + quad * 8;
        short8 a = *(const short8*)&sB[wave * 16 + l16][kb];
#pragma unroll
        for (int ft = 0; ft < 8; ++ft) {
            short8 b = *(const short8*)&sA[ft * 16 + l16][kb];
            acc[ft] = __builtin_amdgcn_mfma_f32_16x16x32_bf16(a, b, acc[ft], 0, 0, 0);
        }
    }
    float dv[4];
#pragma unroll
    for (int r = 0; r < 4; ++r) {
        int gn = n0g + wave * 16 + quad * 4 + r;
        if (gn >= Nn) gn = Nn - 1;
        dv[r] = dinv[gn];
    }
    __syncthreads();  // reuse sA as transpose buffer (s16 fixed-point now)
    unsigned short (*sC)[136] = sA;
#pragma unroll
    for (int ft = 0; ft < 8; ++ft)
#pragma unroll
        for (int r = 0; r < 4; ++r)
            sC[wave * 16 + quad * 4 + r][ft * 16 + l16] = q13(dv[r] * acc[ft][r]);
    __syncthreads();
#pragma unroll
    for (int l = 0; l < 4; ++l) {
        int idx = tid + l * 256;
        int row = idx >> 4, g = idx & 15;
        int gn = n0g + row;
        if (gn < Nn) {
            ushort4 A = *(ushort4*)&sC[row][g * 4];
            ushort4 B = *(ushort4*)&sC[row][g * 4 + 64];
            uint4 o;
            o.x = (unsigned)A.x | ((unsigned)B.x << 16);
            o.y = (unsigned)A.y | ((unsigned)B.y << 16);
            o.z = (unsigned)A.z | ((unsigned)B.z << 16);
            o.w = (unsigned)A.w | ((unsigned)B.w << 16);
            *(uint4*)&h1[(size_t)gn * 64 + g * 4] = o;
        }
    }
}

// ---------- GEMM2 (MFMA): h2[n] = dinv[n]*(hr @ W2), s16 fixed interleaved ----------
// h2[n][q] u32 = s16(feat q) | s16(feat q+32) << 16, q < 32; scale 2^13
__global__ __launch_bounds__(256) void gemm2_k(const unsigned* __restrict__ hr,
                                               const unsigned short* __restrict__ w2bf,
                                               const float* __restrict__ dinv,
                                               unsigned* __restrict__ h2, int Nn) {
    __shared__ __align__(16) unsigned short sA[64][136];
    __shared__ __align__(16) unsigned short sB[64][136];
    int tid = threadIdx.x;
    int n0g = blockIdx.x * 64;
    {
        const uint4* src = (const uint4*)w2bf;
#pragma unroll
        for (int l = 0; l < 4; ++l) {
            int idx = tid + l * 256;
            int f = idx >> 4, kq = idx & 15;
            *(uint4*)&sA[f][kq * 8] = src[idx];
        }
    }
    {
        const uint4* src = (const uint4*)hr;
#pragma unroll
        for (int l = 0; l < 4; ++l) {
            int idx = tid + l * 256;
            int row = idx >> 4, q = idx & 15;
            int gn = n0g + row; if (gn >= Nn) gn = Nn - 1;
            *(uint4*)&sB[row][q * 8] = src[(size_t)gn * 16 + q];
        }
    }
    __syncthreads();
    int wave = tid >> 6, lane = tid & 63;
    int quad = lane >> 4, l16 = lane & 15;
    f32x4 z = {0.f, 0.f, 0.f, 0.f};
    f32x4 acc[4];
#pragma unroll
    for (int t = 0; t < 4; ++t) acc[t] = z;
#pragma unroll
    for (int kk = 0; kk < 4; ++kk) {
        int kb = kk * 32 + quad * 8;
        short8 a = *(const short8*)&sB[wave * 16 + l16][kb];
#pragma unroll
        for (int ft = 0; ft < 4; ++ft) {
            short8 b = *(const short8*)&sA[ft * 16 + l16][kb];
            acc[ft] = __builtin_amdgcn_mfma_f32_16x16x32_bf16(a, b, acc[ft], 0, 0, 0);
        }
    }
    float dv[4];
#pragma unroll
    for (int r = 0; r < 4; ++r) {
        int gn = n0g + wave * 16 + quad * 4 + r;
        if (gn >= Nn) gn = Nn - 1;
        dv[r] = dinv[gn];
    }
    __syncthreads();
    unsigned short (*sC)[136] = sA;
#pragma unroll
    for (int ft = 0; ft < 4; ++ft)
#pragma unroll
        for (int r = 0; r < 4; ++r)
            sC[wave * 16 + quad * 4 + r][ft * 16 + l16] = q13(dv[r] * acc[ft][r]);
    __syncthreads();
#pragma unroll
    for (int l = 0; l < 2; ++l) {
        int idx = tid + l * 256;
        int row = idx >> 3, g = idx & 7;
        int gn = n0g + row;
        if (gn < Nn) {
            ushort4 A = *(ushort4*)&sC[row][g * 4];
            ushort4 B = *(ushort4*)&sC[row][g * 4 + 32];
            uint4 o;
            o.x = (unsigned)A.x | ((unsigned)B.x << 16);
            o.y = (unsigned)A.y | ((unsigned)B.y << 16);
            o.z = (unsigned)A.z | ((unsigned)B.z << 16);
            o.w = (unsigned)A.w | ((unsigned)B.w << 16);
            *(uint4*)&h2[(size_t)gn * 32 + g * 4] = o;
        }
    }
}

// ---------- agg1: block=bucket(128 dst), s32 LDS accum, s16 gathers, 16 waves ----------
// out[dst] = relu( di * (sum h'[src] + h'[self]) + b ), out packed bf16
__global__ __launch_bounds__(1024) void agg1_k(const unsigned* __restrict__ h,
                                               const unsigned* __restrict__ pairs,
                                               const int* __restrict__ keybase,
                                               const int* __restrict__ tot,
                                               const float* __restrict__ dinv,
                                               const float* __restrict__ bias,
                                               unsigned* __restrict__ out, int Nn) {
    extern __shared__ int iacc[];   // [128][128] s32, scale 2^13
    int tid = threadIdx.x, lane = tid & 63, wave = tid >> 6;
    int b = blockIdx.x, n0 = b << 7;
    // init with self rows (h already dinv-prescaled; word q = feats (q, q+64))
    for (int i = tid; i < 128 * 64; i += 1024) {
        int row = i >> 6, q = i & 63;
        unsigned u = (n0 + row < Nn) ? h[(size_t)(n0 + row) * 64 + q] : 0u;
        iacc[row * 128 + q] = (int)(short)(u & 0xffffu);
        iacc[row * 128 + 64 + q] = ((int)u) >> 16;
    }
    __syncthreads();
    int lo = keybase[b * NCH];
    int hi = (b == NBUCK2 - 1) ? *tot : keybase[(b + 1) * NCH];
    for (int base = lo + wave * 64; base < hi; base += 1024) {
        int idx = base + lane;
        unsigned pv = pairs[(idx < hi) ? idx : (hi - 1)];
        int m = hi - base; if (m > 64) m = 64;
        int j = 0;
        for (; j + 4 <= m; j += 4) {
            unsigned p0 = __shfl(pv, j),     p1 = __shfl(pv, j + 1);
            unsigned p2 = __shfl(pv, j + 2), p3 = __shfl(pv, j + 3);
            unsigned u0 = h[((p0 & 0x1FFFFu) << 6) + lane];
            unsigned u1 = h[((p1 & 0x1FFFFu) << 6) + lane];
            unsigned u2 = h[((p2 & 0x1FFFFu) << 6) + lane];
            unsigned u3 = h[((p3 & 0x1FFFFu) << 6) + lane];
            int* a0 = &iacc[((p0 >> 17) << 7) + lane];
            atomicAdd(a0, (int)(short)(u0 & 0xffffu)); atomicAdd(a0 + 64, ((int)u0) >> 16);
            int* a1 = &iacc[((p1 >> 17) << 7) + lane];
            atomicAdd(a1, (int)(short)(u1 & 0xffffu)); atomicAdd(a1 + 64, ((int)u1) >> 16);
            int* a2 = &iacc[((p2 >> 17) << 7) + lane];
            atomicAdd(a2, (int)(short)(u2 & 0xffffu)); atomicAdd(a2 + 64, ((int)u2) >> 16);
            int* a3 = &iacc[((p3 >> 17) << 7) + lane];
            atomicAdd(a3, (int)(short)(u3 & 0xffffu)); atomicAdd(a3 + 64, ((int)u3) >> 16);
        }
        for (; j < m; ++j) {
            unsigned p = __shfl(pv, j);
            unsigned u = h[((p & 0x1FFFFu) << 6) + lane];
            int* a = &iacc[((p >> 17) << 7) + lane];
            atomicAdd(a, (int)(short)(u & 0xffffu)); atomicAdd(a + 64, ((int)u) >> 16);
        }
    }
    __syncthreads();
    int nn = Nn - n0; if (nn > 128) nn = 128;
    for (int i = tid; i < nn * 64; i += 1024) {
        int row = i >> 6, q = i & 63;
        float di = dinv[n0 + row];
        float sx = (float)iacc[row * 128 + 2 * q] * IQS;
        float sy = (float)iacc[row * 128 + 2 * q + 1] * IQS;
        float r0 = fmaxf(fmaf(di, sx, bias[2 * q]), 0.f);
        float r1 = fmaxf(fmaf(di, sy, bias[2 * q + 1]), 0.f);
        out[(size_t)(n0 + row) * 64 + q] = packbf(r0, r1);
    }
}

// ---------- agg2: block=bucket(128 dst), 32KB s32 accum, 2 edges/step, 16 waves ----------
__global__ __launch_bounds__(1024) void agg2_k(const unsigned* __restrict__ h,
                                               const unsigned* __restrict__ pairs,
                                               const int* __restrict__ keybase,
                                               const int* __restrict__ tot,
                                               const float* __restrict__ dinv,
                                               const float* __restrict__ bias,
                                               float* __restrict__ out, int Nn) {
    __shared__ int iacc[128 * 64];
    int tid = threadIdx.x, lane = tid & 63, wave = tid >> 6;
    int half = lane >> 5, fl = lane & 31;
    int b = blockIdx.x, n0 = b << 7;
    for (int i = tid; i < 128 * 32; i += 1024) {
        int row = i >> 5, q = i & 31;
        unsigned u = (n0 + row < Nn) ? h[(size_t)(n0 + row) * 32 + q] : 0u;
        iacc[row * 64 + q] = (int)(short)(u & 0xffffu);
        iacc[row * 64 + 32 + q] = ((int)u) >> 16;
    }
    __syncthreads();
    int lo = keybase[b * NCH];
    int hi = (b == NBUCK2 - 1) ? *tot : keybase[(b + 1) * NCH];
    for (int base = lo + wave * 64; base < hi; base += 1024) {
        int idx = base + lane;
        unsigned pv = pairs[(idx < hi) ? idx : (hi - 1)];
        int m = hi - base; if (m > 64) m = 64;
        int j = 0;
        for (; j + 8 <= m; j += 8) {
            unsigned p0 = __shfl(pv, j + half);
            unsigned p1 = __shfl(pv, j + 2 + half);
            unsigned p2 = __shfl(pv, j + 4 + half);
            unsigned p3 = __shfl(pv, j + 6 + half);
            unsigned u0 = h[((p0 & 0x1FFFFu) << 5) + fl];
            unsigned u1 = h[((p1 & 0x1FFFFu) << 5) + fl];
            unsigned u2 = h[((p2 & 0x1FFFFu) << 5) + fl];
            unsigned u3 = h[((p3 & 0x1FFFFu) << 5) + fl];
            int* a0 = &iacc[((p0 >> 17) << 6) + fl];
            atomicAdd(a0, (int)(short)(u0 & 0xffffu)); atomicAdd(a0 + 32, ((int)u0) >> 16);
            int* a1 = &iacc[((p1 >> 17) << 6) + fl];
            atomicAdd(a1, (int)(short)(u1 & 0xffffu)); atomicAdd(a1 + 32, ((int)u1) >> 16);
            int* a2 = &iacc[((p2 >> 17) << 6) + fl];
            atomicAdd(a2, (int)(short)(u2 & 0xffffu)); atomicAdd(a2 + 32, ((int)u2) >> 16);
            int* a3 = &iacc[((p3 >> 17) << 6) + fl];
            atomicAdd(a3, (int)(short)(u3 & 0xffffu)); atomicAdd(a3 + 32, ((int)u3) >> 16);
        }
        for (; j < m; j += 2) {
            int q = j + half;
            unsigned p = __shfl(pv, (q < m) ? q : j);
            if (q < m) {
                unsigned u = h[((p & 0x1FFFFu) << 5) + fl];
                int* a = &iacc[((p >> 17) << 6) + fl];
                atomicAdd(a, (int)(short)(u & 0xffffu)); atomicAdd(a + 32, ((int)u) >> 16);
            }
        }
    }
    __syncthreads();
    int nn = Nn - n0; if (nn > 128) nn = 128;
    for (int i = tid; i < nn * 64; i += 1024) {
        int row = i >> 6, f = i & 63;
        float di = dinv[n0 + row];
        float s = (float)iacc[row * 64 + f] * IQS;
        out[(size_t)(n0 + row) * 64 + f] = fmaf(di, s, bias[f]);
    }
}

// ---------- launch ----------
extern "C" void kernel_launch(void* const* d_in, const int* in_sizes, int n_in,
                              void* d_out, int out_size, void* d_ws, size_t ws_size,
                              hipStream_t stream) {
    const float* x  = (const float*)d_in[0];
    const void*  ei = d_in[1];
    const float* W1 = (const float*)d_in[2];
    const float* b1 = (const float*)d_in[3];
    const float* W2 = (const float*)d_in[4];
    const float* b2 = (const float*)d_in[5];

    const int N = N_NODES;
    const int E = in_sizes[1] / 2;

    char* w = (char*)d_ws;
    size_t off = 0;
    auto take = [&](size_t bytes) {
        void* p = w + off;
        off = (off + bytes + 255) & ~(size_t)255;
        return p;
    };
    int*   flag    = (int*)take(2 * sizeof(int));
    int*   tot     = flag + 1;
    int*   cnt     = (int*)take((size_t)N * 4);
    int*   bsumB   = (int*)take(4096 * 4);
    int*   colsum  = (int*)take((size_t)NKEY * 4);
    int*   keybase = (int*)take((size_t)NKEY * 4);
    float* dinv    = (float*)take((size_t)N * 4);
    unsigned* pairs = (unsigned*)take((size_t)E * 4);
    unsigned short* w1bf = (unsigned short*)take(128 * 128 * 2);
    unsigned short* w2bf = (unsigned short*)take(64 * 128 * 2);
    unsigned* hr   = (unsigned*)take((size_t)N * 64 * 4);   // bf16 [N][128] normal order
    unsigned* h2   = (unsigned*)take((size_t)N * 32 * 4);   // s16-fixed [N][64] interleaved
    (void)ws_size; (void)n_in; (void)out_size;

    // Staging tables ALIAS onto hr/h2 (both dead until after staging):
    //   bhist last read by colprefix_k; hr first written by agg1_k (later).
    //   bbase last read by write1_k;   h2 first written by gemm2_k (later).
    int* bhist = (int*)hr;
    int* bbase = (int*)h2;

    unsigned* h1 = (unsigned*)d_out;  // s16-fixed [N][128] interleaved, dead before agg2 writes

    const int nscanK = (NKEY + 1023) / 1024;   // 10
    const int ngridK = (NKEY + 255) / 256;     // 40

    detect64_k<<<1, 64, 0, stream>>>((const unsigned long long*)ei, flag);
    count1_k<<<NBLK2, 256, 0, stream>>>(ei, flag, bhist, E);
    colsum_k<<<ngridK, 256, 0, stream>>>(bhist, colsum);
    scan1_k<<<nscanK, 256, 0, stream>>>(colsum, keybase, bsumB, NKEY);
    scan2_k<<<1, 256, 0, stream>>>(bsumB, nscanK);
    scanadd_k<<<nscanK, 256, 0, stream>>>(bsumB, keybase, colsum, tot, NKEY);
    colprefix_k<<<ngridK, 256, 0, stream>>>(bhist, keybase, bbase);
    write1_k<<<NBLK2, 256, 0, stream>>>(ei, flag, bbase, pairs, E);
    degree_k<<<NBUCK2, 256, 0, stream>>>(pairs, keybase, tot, cnt, N);
    dinv_k<<<(N + 255) / 256, 256, 0, stream>>>(cnt, dinv, N);
    prep_w_k<<<64, 256, 0, stream>>>(W1, W2, w1bf, w2bf);

    gemm1_k<<<(N + 63) / 64, 256, 0, stream>>>(x, w1bf, dinv, h1, N);
    agg1_k<<<NBUCK2, 1024, 128 * 128 * 4, stream>>>(h1, pairs, keybase, tot, dinv, b1, hr, N);
    gemm2_k<<<(N + 63) / 64, 256, 0, stream>>>(hr, w2bf, dinv, h2, N);
    agg2_k<<<NBUCK2, 1024, 0, stream>>>(h2, pairs, keybase, tot, dinv, b2, (float*)d_out, N);
}